// Round 6
// baseline (3092.450 us; speedup 1.0000x reference)
//
#include <hip/hip_runtime.h>
#include <stdint.h>

// GGNN round 20: persistent mega with cross-tile async staging (T14).
// r19 banked 1224.5us (mega2 83.7, gather3_c ~58/iter). mega2's remaining
// 40% idle = staging drain: {issue 33KB loads -> barrier -> compute} exposes
// ~900cy HBM latency at 2 blocks/CU. Fix WITHOUT touching the 196-reg
// cliff: persistent grid (512 = 2/CU), each block loops tiles; during tile
// t's compute it ISSUES tile t+512's loads into 32 prefetch VGPRs (~228
// unified < 256 cap), committing to LDS at next loop head. Latency hides
// under ~1600cy of MFMA+epilogue. GRU coeffs hoisted out of the loop.
// Added barrier between gh reads and in-place Ax write (r14 latent race).
// No-spill check: WRITE_SIZE must stay 25.0MB.

typedef _Float16 f16;
typedef _Float16 v8hf __attribute__((ext_vector_type(8)));
typedef _Float16 v2hf __attribute__((ext_vector_type(2)));
typedef float    v16f __attribute__((ext_vector_type(16)));

#define GI_F 147456   // 12 tiles * 24 ks * 512
#define GH_F 49152    // 12 tiles *  8 ks * 512

__device__ __forceinline__ float sigf(float a){
  return __fdividef(1.0f, 1.0f + __expf(-a));
}
__device__ __forceinline__ float tanhf_fast(float a){
  return 1.0f - __fdividef(2.0f, __expf(2.0f*a) + 1.0f);
}

__global__ void k_diag(float* out, int n, float v){
  int i = threadIdx.x; if(i<n) out[i] = v;
}

__global__ void k_embed(const int* __restrict__ xtype, const int* __restrict__ xtok,
                        const float* __restrict__ xsmall,
                        const float* __restrict__ temb, const float* __restrict__ kemb,
                        f16* __restrict__ xb, int N){
  int n = blockIdx.x; int j = threadIdx.x;
  if(n>=N) return;
  float v;
  if(j<32)       v = temb[xtype[n]*32 + j];
  else if(j<64)  v = kemb[xtok[n]*32 + (j-32)];
  else           v = xsmall[(size_t)n*64 + (j-64)];
  xb[(size_t)n*128 + j] = (f16)v;
}

// Wc[o2][K] = sum_k2 W_ih[o2,k2] * msg_W[K>>7][k2][K&127]
__global__ void k_wcomb(const float* __restrict__ W_ih, const float* __restrict__ msg_W,
                        float* __restrict__ Wc){
  int i = blockIdx.x*256 + threadIdx.x;
  if(i >= 147456) return;
  int o2 = i/384, K = i%384;
  const float* wr = W_ih + o2*128;
  const float* mc = msg_W + (K>>7)*16384 + (K&127);
  float acc = 0.f;
  #pragma unroll 4
  for(int k2=0;k2<128;k2++) acc += wr[k2]*mc[k2*128];
  Wc[i] = acc;
}

// mbp[t][o2] = sum_k2 W_ih[o2,k2]*msg_b[t,k2]
__global__ void k_mbp(const float* __restrict__ W_ih, const float* __restrict__ msg_b,
                      float* __restrict__ mbp){
  int i = blockIdx.x*256 + threadIdx.x;
  if(i >= 1152) return;
  int t = i/384, o2 = i%384;
  const float* wr = W_ih + o2*128;
  const float* mb = msg_b + t*128;
  float acc = 0.f;
  #pragma unroll 4
  for(int k2=0;k2<128;k2++) acc += wr[k2]*mb[k2];
  mbp[i] = acc;
}

// Pack weights f16, MFMA B-frag order: n = tile*32+(lane&31), k = ks*16+(lane>>5)*8+j
__global__ void k_wprep(const float* __restrict__ Wc, const float* __restrict__ W_hh,
                        f16* __restrict__ WpF){
  int i = blockIdx.x*256 + threadIdx.x;
  if(i >= GI_F + GH_F) return;
  float w; int lane, j;
  if(i < GI_F){
    int grp = i/512, rem = i%512;
    lane = rem/8; j = rem%8;
    int tile = grp/24, ks = grp%24;
    int n = tile*32 + (lane&31);
    int k = ks*16 + (lane>>5)*8 + j;
    w = Wc[n*384 + k];
  } else {
    int i2 = i - GI_F;
    int grp = i2/512, rem = i2%512;
    lane = rem/8; j = rem%8;
    int tile = grp/8, ks = grp%8;
    int n = tile*32 + (lane&31);
    int k = ks*16 + (lane>>5)*8 + j;
    w = W_hh[n*128 + k];
  }
  WpF[i] = (f16)w;
}

__global__ void k_hist3(const int* __restrict__ dst, const int* __restrict__ et,
                        int* __restrict__ deg3, int E){
  int e = blockIdx.x*blockDim.x + threadIdx.x;
  if(e<E) atomicAdd(&deg3[dst[e]*3 + et[e]], 1);
}

__global__ void k_scan1(const int* __restrict__ deg, int n, int* __restrict__ part, int* __restrict__ bsum){
  __shared__ int s[256];
  int t = threadIdx.x;
  int base = blockIdx.x*1024 + t*4;
  int v[4]; int sum=0;
  #pragma unroll
  for(int k=0;k<4;k++){ int i=base+k; int d=(i<n)?deg[i]:0; sum+=d; v[k]=sum; }
  s[t]=sum; __syncthreads();
  for(int off=1;off<256;off<<=1){
    int add = (t>=off)? s[t-off] : 0;
    __syncthreads();
    s[t]+=add;
    __syncthreads();
  }
  int excl = (t>0)? s[t-1] : 0;
  #pragma unroll
  for(int k=0;k<4;k++){ int i=base+k; if(i<n) part[i]=v[k]+excl; }
  if(t==255) bsum[blockIdx.x] = s[255];
}

__global__ void k_scan2(const int* __restrict__ bsum, int nb, int* __restrict__ carry){
  if(threadIdx.x==0 && blockIdx.x==0){
    int c=0;
    for(int b=0;b<nb;b++){ carry[b]=c; c+=bsum[b]; }
  }
}

__global__ void k_finalize(const int* __restrict__ part, const int* __restrict__ deg,
                           const int* __restrict__ carry, int n,
                           int* __restrict__ rowptr, int* __restrict__ cursor){
  int i = blockIdx.x*blockDim.x + threadIdx.x;
  if(i>=n) return;
  int incl = part[i] + carry[i>>10];
  rowptr[i+1] = incl;
  cursor[i] = incl - deg[i];
  if(i==0) rowptr[0]=0;
}

__global__ void k_fill3(const int* __restrict__ src, const int* __restrict__ dst,
                        const int* __restrict__ et, int* __restrict__ cursor,
                        int* __restrict__ pay, int E){
  int e = blockIdx.x*blockDim.x + threadIdx.x;
  if(e>=E) return;
  int pos = atomicAdd(&cursor[dst[e]*3 + et[e]], 1);
  pay[pos] = src[e];
}

// gather: one wave per node. 3-stream flat split of the node's full CSR
// range [lo,hi): balanced thirds keep 3 row-loads in flight even when the
// per-type chains are unbalanced. Type bin from wave-uniform compares.
__global__ void k_gather3_c(const f16* __restrict__ xb, const int* __restrict__ rp3,
                            const int* __restrict__ pay, f16* __restrict__ s, int N){
  int n = blockIdx.x*4 + (threadIdx.x>>6);
  if(n >= N) return;
  int lane = threadIdx.x & 63;
  int c = lane*2;
  int b = n*3;
  int lo = rp3[b], e0 = rp3[b+1], e1 = rp3[b+2], hi = rp3[b+3];
  float a0=0.f,b0=0.f,a1=0.f,b1=0.f,a2=0.f,b2=0.f;
  int len = hi - lo;
  int t1 = lo + len/3;
  int t2 = lo + (2*len)/3;
  int iA = lo, iB = t1, iC = t2;
  while(iA < t1 && iB < t2 && iC < hi){
    int pA = pay[iA], pB = pay[iB], pC = pay[iC];
    v2hf uA = *(const v2hf*)&xb[(size_t)pA*128 + c];
    v2hf uB = *(const v2hf*)&xb[(size_t)pB*128 + c];
    v2hf uC = *(const v2hf*)&xb[(size_t)pC*128 + c];
    float fA0=(float)uA[0], fA1=(float)uA[1];
    float fB0=(float)uB[0], fB1=(float)uB[1];
    float fC0=(float)uC[0], fC1=(float)uC[1];
    if(iA < e0)      { a0+=fA0; b0+=fA1; }
    else if(iA < e1) { a1+=fA0; b1+=fA1; }
    else             { a2+=fA0; b2+=fA1; }
    if(iB < e0)      { a0+=fB0; b0+=fB1; }
    else if(iB < e1) { a1+=fB0; b1+=fB1; }
    else             { a2+=fB0; b2+=fB1; }
    if(iC < e0)      { a0+=fC0; b0+=fC1; }
    else if(iC < e1) { a1+=fC0; b1+=fC1; }
    else             { a2+=fC0; b2+=fC1; }
    iA++; iB++; iC++;
  }
  for(; iA < t1; iA++){
    v2hf u = *(const v2hf*)&xb[(size_t)pay[iA]*128 + c];
    float f0=(float)u[0], f1=(float)u[1];
    if(iA < e0)      { a0+=f0; b0+=f1; }
    else if(iA < e1) { a1+=f0; b1+=f1; }
    else             { a2+=f0; b2+=f1; }
  }
  for(; iB < t2; iB++){
    v2hf u = *(const v2hf*)&xb[(size_t)pay[iB]*128 + c];
    float f0=(float)u[0], f1=(float)u[1];
    if(iB < e0)      { a0+=f0; b0+=f1; }
    else if(iB < e1) { a1+=f0; b1+=f1; }
    else             { a2+=f0; b2+=f1; }
  }
  for(; iC < hi; iC++){
    v2hf u = *(const v2hf*)&xb[(size_t)pay[iC]*128 + c];
    float f0=(float)u[0], f1=(float)u[1];
    if(iC < e0)      { a0+=f0; b0+=f1; }
    else if(iC < e1) { a1+=f0; b1+=f1; }
    else             { a2+=f0; b2+=f1; }
  }
  size_t o = (size_t)n*384 + c;
  v2hf t;
  t[0]=(f16)a0; t[1]=(f16)b0; *(v2hf*)&s[o]     = t;
  t[0]=(f16)a1; t[1]=(f16)b1; *(v2hf*)&s[o+128] = t;
  t[0]=(f16)a2; t[1]=(f16)b2; *(v2hf*)&s[o+256] = t;
}

// Persistent fused gi+gh GEMM + GRU, f16 master. 32 rows/tile, 256 threads
// (4 waves), grid 512 (2 blocks/CU). Per tile: commit prefetched regs to
// LDS -> issue next tile's loads -> gi MFMAs -> pack -> gh MFMAs ->
// [barrier] -> GRU epilogue -> writeback. Compute core verbatim r14 mega2.
#define SSTR 392   // 384+8
#define XSTR 136   // 128+8
__global__ __launch_bounds__(256,2) void k_megap(
    const f16* __restrict__ xb_old, f16* __restrict__ xb_new,
    const f16* __restrict__ s, const f16* __restrict__ WpF,
    const int* __restrict__ deg3, const float* __restrict__ mbp,
    const float* __restrict__ b_ih, const float* __restrict__ b_hh,
    int M, int nblk)
{
  __shared__ f16 Ss[32*SSTR];   // 24.5 KB
  __shared__ f16 Ax[32*XSTR];   //  8.5 KB
  __shared__ float Dg[96];      // deg3 for this tile's 32 rows
  int tid = threadIdx.x, lane = tid & 63, w = tid >> 6;
  int lrow = lane & 31, q = lane >> 5;

  // loop-invariant GRU coefficients for this lane's feature jf
  int jf = w*32 + lrow;
  float bi0 = b_ih[jf],     bh0 = b_hh[jf];
  float bi1 = b_ih[128+jf], bh1 = b_hh[128+jf];
  float bi2 = b_ih[256+jf], bh2 = b_hh[256+jf];
  float mb[3][3];
  #pragma unroll
  for(int t=0;t<3;t++){
    mb[t][0] = mbp[t*384 + jf];
    mb[t][1] = mbp[t*384 + 128 + jf];
    mb[t][2] = mbp[t*384 + 256 + jf];
  }
  int rq4 = 4*q;

  // prefetch register state (32 VGPRs live through compute)
  v8hf pf_s[6], pf_x[2];
  float pf_d = 0.f;
  // chunk mappings (constant per thread)
  int s_row[6], s_c8[6], x_row[2], x_c8[2];
  #pragma unroll
  for(int p=0;p<6;p++){ int ch = tid + p*256; s_row[p] = ch/48; s_c8[p] = (ch%48)*8; }
  #pragma unroll
  for(int p=0;p<2;p++){ int ch = tid + p*256; x_row[p] = ch>>4; x_c8[p] = (ch&15)*8; }
  int dg_node3 = (tid/3)*3, dg_t = tid - dg_node3;  // tid<96 only

  int tile = blockIdx.x;
  // prologue prefetch
  {
    int r0 = tile*32;
    #pragma unroll
    for(int p=0;p<6;p++){ int gr = r0 + s_row[p]; if(gr >= M) gr = M-1;
      pf_s[p] = *(const v8hf*)(s + (size_t)gr*384 + s_c8[p]); }
    #pragma unroll
    for(int p=0;p<2;p++){ int gr = r0 + x_row[p]; if(gr >= M) gr = M-1;
      pf_x[p] = *(const v8hf*)(xb_old + (size_t)gr*128 + x_c8[p]); }
    if(tid < 96){ int node = r0 + tid/3;
      pf_d = (node < M) ? (float)deg3[node*3 + dg_t] : 0.f; }
  }

  for(; tile < nblk; tile += gridDim.x){
    int row0 = tile*32;
    __syncthreads();                 // previous tile fully done with LDS
    // commit prefetched regs -> LDS
    #pragma unroll
    for(int p=0;p<6;p++) *(v8hf*)&Ss[s_row[p]*SSTR + s_c8[p]] = pf_s[p];
    #pragma unroll
    for(int p=0;p<2;p++) *(v8hf*)&Ax[x_row[p]*XSTR + x_c8[p]] = pf_x[p];
    if(tid < 96) Dg[tid] = pf_d;
    __syncthreads();
    // issue next tile's loads (hidden under compute below)
    {
      int nt = tile + gridDim.x; if(nt >= nblk) nt = tile;
      int r0 = nt*32;
      #pragma unroll
      for(int p=0;p<6;p++){ int gr = r0 + s_row[p]; if(gr >= M) gr = M-1;
        pf_s[p] = *(const v8hf*)(s + (size_t)gr*384 + s_c8[p]); }
      #pragma unroll
      for(int p=0;p<2;p++){ int gr = r0 + x_row[p]; if(gr >= M) gr = M-1;
        pf_x[p] = *(const v8hf*)(xb_old + (size_t)gr*128 + x_c8[p]); }
      if(tid < 96){ int node = r0 + tid/3;
        pf_d = (node < M) ? (float)deg3[node*3 + dg_t] : 0.f; }
    }

    // ---- gi phase: K=384 over Ss ----
    v16f agi[3] = {};
    #pragma unroll
    for(int ks=0; ks<24; ks++){
      int kb = ks*16 + q*8;
      v8hf a0 = *(const v8hf*)&Ss[lrow*SSTR + kb];
      #pragma unroll
      for(int ct=0; ct<3; ct++){
        int tile_b = ct*4 + w;
        v8hf bh = *(const v8hf*)(WpF + (size_t)(tile_b*24 + ks)*512 + lane*8);
        agi[ct] = __builtin_amdgcn_mfma_f32_32x32x16_f16(a0, bh, agi[ct], 0,0,0);
      }
    }
    // pack agi -> f16 pairs in registers
    v2hf gip[3][8];
    #pragma unroll
    for(int ct=0; ct<3; ct++)
      #pragma unroll
      for(int rp=0; rp<8; rp++){
        v2hf t; t[0] = (f16)agi[ct][2*rp]; t[1] = (f16)agi[ct][2*rp+1];
        gip[ct][rp] = t;
      }

    // ---- gh phase: K=128 over Ax ----
    v16f agh[3] = {};
    #pragma unroll
    for(int ks=0; ks<8; ks++){
      int kb = ks*16 + q*8;
      v8hf a0 = *(const v8hf*)&Ax[lrow*XSTR + kb];
      #pragma unroll
      for(int ct=0; ct<3; ct++){
        int tile_b = ct*4 + w;
        v8hf bh = *(const v8hf*)(WpF + GI_F + (size_t)(tile_b*8 + ks)*512 + lane*8);
        agh[ct] = __builtin_amdgcn_mfma_f32_32x32x16_f16(a0, bh, agh[ct], 0,0,0);
      }
    }

    __syncthreads();   // all waves' gh reads of Ax done before in-place write

    // GRU epilogue in-register; x_old from LDS; in-place Ax update.
    #pragma unroll
    for(int r=0;r<16;r++){
      int gl = (r&3) + 8*(r>>2) + rq4;          // local row 0..31
      float d0 = Dg[gl*3], d1 = Dg[gl*3+1], d2 = Dg[gl*3+2];
      float g0 = (float)gip[0][r>>1][r&1];
      float g1 = (float)gip[1][r>>1][r&1];
      float g2 = (float)gip[2][r>>1][r&1];
      float ir  = g0 + bi0 + d0*mb[0][0] + d1*mb[1][0] + d2*mb[2][0];
      float iz  = g1 + bi1 + d0*mb[0][1] + d1*mb[1][1] + d2*mb[2][1];
      float in_ = g2 + bi2 + d0*mb[0][2] + d1*mb[1][2] + d2*mb[2][2];
      float hr  = agh[0][r] + bh0;
      float hz  = agh[1][r] + bh1;
      float hn  = agh[2][r] + bh2;
      float rg = sigf(ir + hr);
      float zg = sigf(iz + hz);
      float nn = tanhf_fast(in_ + rg*hn);
      float xo = (float)Ax[gl*XSTR + jf];
      Ax[gl*XSTR + jf] = (f16)((1.f - zg)*nn + zg*xo);   // own slot
    }
    __syncthreads();
    // coalesced writeback from Ax
    #pragma unroll
    for(int p=0;p<2;p++){
      int gr = row0 + x_row[p];
      if(gr < M)
        *(v8hf*)(xb_new + (size_t)gr*128 + x_c8[p]) = *(const v8hf*)&Ax[x_row[p]*XSTR + x_c8[p]];
    }
  }
}

__device__ __forceinline__ int lb_batch(const int* __restrict__ batch, int N, int g){
  int lo=0, hi=N;
  while(lo<hi){ int mid=(lo+hi)>>1; if(batch[mid]<g) lo=mid+1; else hi=mid; }
  return lo;
}

__global__ void k_pool2(const f16* __restrict__ xb, const int* __restrict__ batch,
                        float* __restrict__ pooled, int N){
  int g = blockIdx.x, slice = blockIdx.y;
  int j = threadIdx.x;
  int lo = lb_batch(batch,N,g), hi = lb_batch(batch,N,g+1);
  float acc = 0.f;
  for(int r=lo+slice; r<hi; r+=32) acc += (float)xb[(size_t)r*128 + j];
  atomicAdd(&pooled[g*128+j], acc);
}

__global__ void k_head(const float* __restrict__ pooled, const int* __restrict__ batch, int N,
                       const float* __restrict__ W1, const float* __restrict__ b1,
                       const float* __restrict__ W2, const float* __restrict__ b2,
                       float* __restrict__ out){
  int g = blockIdx.x; int j = threadIdx.x;
  __shared__ float p[128];
  __shared__ float red[128];
  int lo = lb_batch(batch,N,g), hi = lb_batch(batch,N,g+1);
  float c = (float)(hi-lo); if(c < 1.f) c = 1.f;
  p[j] = pooled[g*128+j] / c;
  __syncthreads();
  float acc = b1[j];
  #pragma unroll 4
  for(int i=0;i<128;i++) acc += W1[j*128+i]*p[i];
  float v = (acc>0.f?acc:0.f) * W2[j];
  red[j] = v; __syncthreads();
  for(int s=64;s>0;s>>=1){ if(j<s) red[j]+=red[j+s]; __syncthreads(); }
  if(j==0) out[g] = red[0] + b2[0];
}

extern "C" void kernel_launch(void* const* d_in, const int* in_sizes, int n_in,
                              void* d_out, int out_size, void* d_ws, size_t ws_size,
                              hipStream_t stream){
  const int*   x_type    = (const int*)d_in[0];
  const int*   x_tok     = (const int*)d_in[1];
  const float* x_small   = (const float*)d_in[2];
  const int*   edge_index= (const int*)d_in[3];
  const int*   edge_type = (const int*)d_in[4];
  const int*   batch     = (const int*)d_in[5];
  const float* type_emb  = (const float*)d_in[6];
  const float* tok_emb   = (const float*)d_in[7];
  const float* msg_W     = (const float*)d_in[8];
  const float* msg_b     = (const float*)d_in[9];
  const float* W_ih      = (const float*)d_in[10];
  const float* W_hh      = (const float*)d_in[11];
  const float* b_ih      = (const float*)d_in[12];
  const float* b_hh      = (const float*)d_in[13];
  const float* pW1       = (const float*)d_in[14];
  const float* pb1       = (const float*)d_in[15];
  const float* pW2       = (const float*)d_in[16];
  const float* pb2       = (const float*)d_in[17];
  float* out = (float*)d_out;

  int N = in_sizes[0];
  int E = in_sizes[3]/2;
  const int* src = edge_index;
  const int* dst = edge_index + E;
  int n3 = 3*N;
  int nch = (n3+1023)/1024;

  char* w = (char*)d_ws;
  size_t off = 0;
  auto alloc = [&](size_t bytes)->char*{ char* p = w + off; off += (bytes + 511) & ~511ull; return p; };
  f16*   xb0    = (f16*)alloc((size_t)N*128*2);       // ping (25.6 MB)
  f16*   xb1    = (f16*)alloc((size_t)N*128*2);       // pong (25.6 MB)
  f16*   s      = (f16*)alloc((size_t)N*384*2);       // gathered sums (76.8 MB)
  int*   deg3   = (int*)alloc((size_t)n3*4);
  int*   part   = (int*)alloc((size_t)n3*4);
  int*   rp3    = (int*)alloc((size_t)(n3+1)*4);
  int*   cursor = (int*)alloc((size_t)n3*4);
  int*   pay    = (int*)alloc((size_t)E*4);
  int*   bsum   = (int*)alloc((size_t)nch*4);
  int*   carry  = (int*)alloc((size_t)nch*4);
  float* Wc     = (float*)alloc((size_t)147456*4);
  f16*   WpF    = (f16*)alloc((size_t)(GI_F+GH_F)*2);
  float* mbp    = (float*)alloc((size_t)1152*4);
  float* pooled = (float*)alloc(64*128*4);
  if(off > ws_size){
    k_diag<<<1,64,0,stream>>>(out, out_size, 1.0e6f + (float)(ws_size>>20));
    return;
  }

  const int tb = 256;
  hipMemsetAsync(deg3, 0, (size_t)n3*4, stream);
  k_wcomb   <<<576, 256, 0, stream>>>(W_ih, msg_W, Wc);
  k_mbp     <<<5, 256, 0, stream>>>(W_ih, msg_b, mbp);
  k_wprep   <<<(GI_F+GH_F+255)/256, 256, 0, stream>>>(Wc, W_hh, WpF);
  k_hist3   <<<(E+tb-1)/tb, tb, 0, stream>>>(dst, edge_type, deg3, E);
  k_scan1   <<<nch, 256, 0, stream>>>(deg3, n3, part, bsum);
  k_scan2   <<<1, 64, 0, stream>>>(bsum, nch, carry);
  k_finalize<<<(n3+tb-1)/tb, tb, 0, stream>>>(part, deg3, carry, n3, rp3, cursor);
  k_fill3   <<<(E+tb-1)/tb, tb, 0, stream>>>(src, dst, edge_type, cursor, pay, E);
  k_embed   <<<N, 128, 0, stream>>>(x_type, x_tok, x_small, type_emb, tok_emb, xb0, N);

  int nblk = (N+31)/32;
  int pgrid = 512;                   // 2 blocks/CU x 256 CUs
  if(pgrid > nblk) pgrid = nblk;
  f16* xin = xb0;
  f16* xout = xb1;
  for(int it=0; it<8; it++){
    k_gather3_c<<<(N+3)/4, 256, 0, stream>>>(xin, rp3, pay, s, N);
    k_megap    <<<pgrid, 256, 0, stream>>>(xin, xout, s, WpF, deg3, mbp, b_ih, b_hh, N, nblk);
    f16* tmp = xin; xin = xout; xout = tmp;
  }
  // final state is in xin after the swap
  hipMemsetAsync(pooled, 0, 64*128*4, stream);
  k_pool2<<<dim3(64,32), 128, 0, stream>>>(xin, batch, pooled, N);
  k_head <<<64, 128, 0, stream>>>(pooled, batch, N, pW1, pb1, pW2, pb2, out);
}

// Round 7
// 1161.178 us; speedup vs baseline: 2.6632x; 2.6632x over previous
//
#include <hip/hip_runtime.h>
#include <stdint.h>

// GGNN round 21: attack the gather's VMEM-issue bound; mega2 is CLOSED for
// structural edits (r16/r18/r20 all spilled: the 196-unified-reg core has
// zero spare regs). Gather analysis: not HBM-bound (~110MB/iter=17us), not
// L2-BW-bound (2.6 of 34.5 TB/s); fits VMEM address-processing: ~1.2M vmem
// instr/dispatch (~16cy TA each) ~= measured 58us. k_gather3_d halves vmem
// instr/edge: 2 nodes per wave (one per 32-lane half), v4hf 8B loads
// (32 lanes x 8B = 256B/row, coalesced); one row-load instr serves 2 edges.
// Divergence between halves is exec-masked (waste ~25%, slots 2x cheaper).
// mega2b = r19 mega2 + barrier between gh LDS reads and in-place Ax write
// (closes a real cross-wave race currently masked by lockstep timing).

typedef _Float16 f16;
typedef _Float16 v8hf __attribute__((ext_vector_type(8)));
typedef _Float16 v4hf __attribute__((ext_vector_type(4)));
typedef _Float16 v2hf __attribute__((ext_vector_type(2)));
typedef float    v16f __attribute__((ext_vector_type(16)));

#define GI_F 147456   // 12 tiles * 24 ks * 512
#define GH_F 49152    // 12 tiles *  8 ks * 512

__device__ __forceinline__ float sigf(float a){
  return __fdividef(1.0f, 1.0f + __expf(-a));
}
__device__ __forceinline__ float tanhf_fast(float a){
  return 1.0f - __fdividef(2.0f, __expf(2.0f*a) + 1.0f);
}

__global__ void k_diag(float* out, int n, float v){
  int i = threadIdx.x; if(i<n) out[i] = v;
}

__global__ void k_embed(const int* __restrict__ xtype, const int* __restrict__ xtok,
                        const float* __restrict__ xsmall,
                        const float* __restrict__ temb, const float* __restrict__ kemb,
                        f16* __restrict__ xb, int N){
  int n = blockIdx.x; int j = threadIdx.x;
  if(n>=N) return;
  float v;
  if(j<32)       v = temb[xtype[n]*32 + j];
  else if(j<64)  v = kemb[xtok[n]*32 + (j-32)];
  else           v = xsmall[(size_t)n*64 + (j-64)];
  xb[(size_t)n*128 + j] = (f16)v;
}

// Wc[o2][K] = sum_k2 W_ih[o2,k2] * msg_W[K>>7][k2][K&127]
__global__ void k_wcomb(const float* __restrict__ W_ih, const float* __restrict__ msg_W,
                        float* __restrict__ Wc){
  int i = blockIdx.x*256 + threadIdx.x;
  if(i >= 147456) return;
  int o2 = i/384, K = i%384;
  const float* wr = W_ih + o2*128;
  const float* mc = msg_W + (K>>7)*16384 + (K&127);
  float acc = 0.f;
  #pragma unroll 4
  for(int k2=0;k2<128;k2++) acc += wr[k2]*mc[k2*128];
  Wc[i] = acc;
}

// mbp[t][o2] = sum_k2 W_ih[o2,k2]*msg_b[t,k2]
__global__ void k_mbp(const float* __restrict__ W_ih, const float* __restrict__ msg_b,
                      float* __restrict__ mbp){
  int i = blockIdx.x*256 + threadIdx.x;
  if(i >= 1152) return;
  int t = i/384, o2 = i%384;
  const float* wr = W_ih + o2*128;
  const float* mb = msg_b + t*128;
  float acc = 0.f;
  #pragma unroll 4
  for(int k2=0;k2<128;k2++) acc += wr[k2]*mb[k2];
  mbp[i] = acc;
}

// Pack weights f16, MFMA B-frag order: n = tile*32+(lane&31), k = ks*16+(lane>>5)*8+j
__global__ void k_wprep(const float* __restrict__ Wc, const float* __restrict__ W_hh,
                        f16* __restrict__ WpF){
  int i = blockIdx.x*256 + threadIdx.x;
  if(i >= GI_F + GH_F) return;
  float w; int lane, j;
  if(i < GI_F){
    int grp = i/512, rem = i%512;
    lane = rem/8; j = rem%8;
    int tile = grp/24, ks = grp%24;
    int n = tile*32 + (lane&31);
    int k = ks*16 + (lane>>5)*8 + j;
    w = Wc[n*384 + k];
  } else {
    int i2 = i - GI_F;
    int grp = i2/512, rem = i2%512;
    lane = rem/8; j = rem%8;
    int tile = grp/8, ks = grp%8;
    int n = tile*32 + (lane&31);
    int k = ks*16 + (lane>>5)*8 + j;
    w = W_hh[n*128 + k];
  }
  WpF[i] = (f16)w;
}

__global__ void k_hist3(const int* __restrict__ dst, const int* __restrict__ et,
                        int* __restrict__ deg3, int E){
  int e = blockIdx.x*blockDim.x + threadIdx.x;
  if(e<E) atomicAdd(&deg3[dst[e]*3 + et[e]], 1);
}

__global__ void k_scan1(const int* __restrict__ deg, int n, int* __restrict__ part, int* __restrict__ bsum){
  __shared__ int s[256];
  int t = threadIdx.x;
  int base = blockIdx.x*1024 + t*4;
  int v[4]; int sum=0;
  #pragma unroll
  for(int k=0;k<4;k++){ int i=base+k; int d=(i<n)?deg[i]:0; sum+=d; v[k]=sum; }
  s[t]=sum; __syncthreads();
  for(int off=1;off<256;off<<=1){
    int add = (t>=off)? s[t-off] : 0;
    __syncthreads();
    s[t]+=add;
    __syncthreads();
  }
  int excl = (t>0)? s[t-1] : 0;
  #pragma unroll
  for(int k=0;k<4;k++){ int i=base+k; if(i<n) part[i]=v[k]+excl; }
  if(t==255) bsum[blockIdx.x] = s[255];
}

__global__ void k_scan2(const int* __restrict__ bsum, int nb, int* __restrict__ carry){
  if(threadIdx.x==0 && blockIdx.x==0){
    int c=0;
    for(int b=0;b<nb;b++){ carry[b]=c; c+=bsum[b]; }
  }
}

__global__ void k_finalize(const int* __restrict__ part, const int* __restrict__ deg,
                           const int* __restrict__ carry, int n,
                           int* __restrict__ rowptr, int* __restrict__ cursor){
  int i = blockIdx.x*blockDim.x + threadIdx.x;
  if(i>=n) return;
  int incl = part[i] + carry[i>>10];
  rowptr[i+1] = incl;
  cursor[i] = incl - deg[i];
  if(i==0) rowptr[0]=0;
}

__global__ void k_fill3(const int* __restrict__ src, const int* __restrict__ dst,
                        const int* __restrict__ et, int* __restrict__ cursor,
                        int* __restrict__ pay, int E){
  int e = blockIdx.x*blockDim.x + threadIdx.x;
  if(e>=E) return;
  int pos = atomicAdd(&cursor[dst[e]*3 + et[e]], 1);
  pay[pos] = src[e];
}

// gather: 2 nodes per wave (one per 32-lane half), lane covers 4 f16 cols
// via one v4hf 8B load (32 lanes x 8B = 256B/row). 3-stream flat split of
// each node's CSR range keeps 3 rows in flight per half (6 per wave). One
// vmem instruction serves both halves' edges -> vmem instr/edge halved vs
// gather3_c. Type bin from per-half-uniform segment compares.
__global__ void k_gather3_d(const f16* __restrict__ xb, const int* __restrict__ rp3,
                            const int* __restrict__ pay, f16* __restrict__ s, int N){
  int tid = threadIdx.x;
  int lane = tid & 63;
  int h = lane >> 5;          // node select within wave
  int c4 = (lane & 31)*4;     // col base (f16 cols)
  int n = blockIdx.x*8 + (tid>>6)*2 + h;
  bool valid = (n < N);
  int nn = valid ? n : (N-1);
  int b = nn*3;
  int lo = rp3[b], e0 = rp3[b+1], e1 = rp3[b+2], hi = rp3[b+3];
  if(!valid){ lo = 0; e0 = 0; e1 = 0; hi = 0; }
  float a00=0.f,a01=0.f,a02=0.f,a03=0.f;
  float a10=0.f,a11=0.f,a12=0.f,a13=0.f;
  float a20=0.f,a21=0.f,a22=0.f,a23=0.f;
  int len = hi - lo;
  int t1 = lo + len/3;
  int t2 = lo + (2*len)/3;
  int iA = lo, iB = t1, iC = t2;
  while(iA < t1 && iB < t2 && iC < hi){
    int pA = pay[iA], pB = pay[iB], pC = pay[iC];
    v4hf uA = *(const v4hf*)&xb[(size_t)pA*128 + c4];
    v4hf uB = *(const v4hf*)&xb[(size_t)pB*128 + c4];
    v4hf uC = *(const v4hf*)&xb[(size_t)pC*128 + c4];
    float fA0=(float)uA[0], fA1=(float)uA[1], fA2=(float)uA[2], fA3=(float)uA[3];
    float fB0=(float)uB[0], fB1=(float)uB[1], fB2=(float)uB[2], fB3=(float)uB[3];
    float fC0=(float)uC[0], fC1=(float)uC[1], fC2=(float)uC[2], fC3=(float)uC[3];
    if(iA < e0)      { a00+=fA0; a01+=fA1; a02+=fA2; a03+=fA3; }
    else if(iA < e1) { a10+=fA0; a11+=fA1; a12+=fA2; a13+=fA3; }
    else             { a20+=fA0; a21+=fA1; a22+=fA2; a23+=fA3; }
    if(iB < e0)      { a00+=fB0; a01+=fB1; a02+=fB2; a03+=fB3; }
    else if(iB < e1) { a10+=fB0; a11+=fB1; a12+=fB2; a13+=fB3; }
    else             { a20+=fB0; a21+=fB1; a22+=fB2; a23+=fB3; }
    if(iC < e0)      { a00+=fC0; a01+=fC1; a02+=fC2; a03+=fC3; }
    else if(iC < e1) { a10+=fC0; a11+=fC1; a12+=fC2; a13+=fC3; }
    else             { a20+=fC0; a21+=fC1; a22+=fC2; a23+=fC3; }
    iA++; iB++; iC++;
  }
  for(; iA < t1; iA++){
    v4hf u = *(const v4hf*)&xb[(size_t)pay[iA]*128 + c4];
    float f0=(float)u[0], f1=(float)u[1], f2=(float)u[2], f3=(float)u[3];
    if(iA < e0)      { a00+=f0; a01+=f1; a02+=f2; a03+=f3; }
    else if(iA < e1) { a10+=f0; a11+=f1; a12+=f2; a13+=f3; }
    else             { a20+=f0; a21+=f1; a22+=f2; a23+=f3; }
  }
  for(; iB < t2; iB++){
    v4hf u = *(const v4hf*)&xb[(size_t)pay[iB]*128 + c4];
    float f0=(float)u[0], f1=(float)u[1], f2=(float)u[2], f3=(float)u[3];
    if(iB < e0)      { a00+=f0; a01+=f1; a02+=f2; a03+=f3; }
    else if(iB < e1) { a10+=f0; a11+=f1; a12+=f2; a13+=f3; }
    else             { a20+=f0; a21+=f1; a22+=f2; a23+=f3; }
  }
  for(; iC < hi; iC++){
    v4hf u = *(const v4hf*)&xb[(size_t)pay[iC]*128 + c4];
    float f0=(float)u[0], f1=(float)u[1], f2=(float)u[2], f3=(float)u[3];
    if(iC < e0)      { a00+=f0; a01+=f1; a02+=f2; a03+=f3; }
    else if(iC < e1) { a10+=f0; a11+=f1; a12+=f2; a13+=f3; }
    else             { a20+=f0; a21+=f1; a22+=f2; a23+=f3; }
  }
  if(valid){
    size_t o = (size_t)n*384 + c4;
    v4hf t;
    t[0]=(f16)a00; t[1]=(f16)a01; t[2]=(f16)a02; t[3]=(f16)a03; *(v4hf*)&s[o]     = t;
    t[0]=(f16)a10; t[1]=(f16)a11; t[2]=(f16)a12; t[3]=(f16)a13; *(v4hf*)&s[o+128] = t;
    t[0]=(f16)a20; t[1]=(f16)a21; t[2]=(f16)a22; t[3]=(f16)a23; *(v4hf*)&s[o+256] = t;
  }
}

// Fused gi+gh GEMM + GRU, f16 master. 32 rows/block, 256 threads (4 waves).
// Wave w col-tiles {w,w+4,w+8} => feature slice jf in [32w,32w+32) across all
// 3 gates for gi AND gh => GRU in-register. r19 core + barrier between the
// gh-phase LDS reads (all waves read all Ax rows/cols) and the in-place Ax
// epilogue write (each wave writes its own col slice) - closes a real race.
#define SSTR 392   // 384+8
#define XSTR 136   // 128+8
__global__ __launch_bounds__(256,2) void k_mega2b(
    const f16* __restrict__ xb_old, f16* __restrict__ xb_new,
    const f16* __restrict__ s, const f16* __restrict__ WpF,
    const int* __restrict__ deg3, const float* __restrict__ mbp,
    const float* __restrict__ b_ih, const float* __restrict__ b_hh, int M)
{
  __shared__ f16 Ss[32*SSTR];   // 24.5 KB
  __shared__ f16 Ax[32*XSTR];   //  8.5 KB
  __shared__ float Dg[96];      // deg3 for this block's 32 rows
  int tid = threadIdx.x, lane = tid & 63, w = tid >> 6;
  int lrow = lane & 31, q = lane >> 5;
  int row0 = blockIdx.x * 32;

  // stage xb rows -> Ax: 512 chunks, 2/thread
  #pragma unroll
  for(int p=0;p<2;p++){
    int ch = tid + p*256;
    int row = ch>>4, c8 = (ch&15)*8;
    int gr = row0 + row; if(gr >= M) gr = M-1;
    *(v8hf*)&Ax[row*XSTR + c8] = *(const v8hf*)(xb_old + (size_t)gr*128 + c8);
  }
  // stage s rows -> Ss: 1536 chunks, 6/thread
  #pragma unroll
  for(int p=0;p<6;p++){
    int ch = tid + p*256;
    int row = ch/48, c8 = (ch%48)*8;
    int gr = row0 + row; if(gr >= M) gr = M-1;
    *(v8hf*)&Ss[row*SSTR + c8] = *(const v8hf*)(s + (size_t)gr*384 + c8);
  }
  // stage deg3 -> Dg
  if(tid < 96){
    int node = row0 + tid/3;
    Dg[tid] = (node < M) ? (float)deg3[node*3 + (tid - (tid/3)*3)] : 0.f;
  }
  __syncthreads();

  // ---- gi phase: K=384 over Ss ----
  v16f agi[3] = {};
  #pragma unroll
  for(int ks=0; ks<24; ks++){
    int kb = ks*16 + q*8;
    v8hf a0 = *(const v8hf*)&Ss[lrow*SSTR + kb];
    #pragma unroll
    for(int ct=0; ct<3; ct++){
      int tile = ct*4 + w;
      v8hf bh = *(const v8hf*)(WpF + (size_t)(tile*24 + ks)*512 + lane*8);
      agi[ct] = __builtin_amdgcn_mfma_f32_32x32x16_f16(a0, bh, agi[ct], 0,0,0);
    }
  }
  // pack agi -> f16 pairs in registers (frees 48 -> 24 regs; no cap => no spill)
  v2hf gip[3][8];
  #pragma unroll
  for(int ct=0; ct<3; ct++)
    #pragma unroll
    for(int rp=0; rp<8; rp++){
      v2hf t; t[0] = (f16)agi[ct][2*rp]; t[1] = (f16)agi[ct][2*rp+1];
      gip[ct][rp] = t;
    }

  // ---- gh phase: K=128 over Ax ----
  v16f agh[3] = {};
  #pragma unroll
  for(int ks=0; ks<8; ks++){
    int kb = ks*16 + q*8;
    v8hf a0 = *(const v8hf*)&Ax[lrow*XSTR + kb];
    #pragma unroll
    for(int ct=0; ct<3; ct++){
      int tile = ct*4 + w;
      v8hf bh = *(const v8hf*)(WpF + GI_F + (size_t)(tile*8 + ks)*512 + lane*8);
      agh[ct] = __builtin_amdgcn_mfma_f32_32x32x16_f16(a0, bh, agh[ct], 0,0,0);
    }
  }

  __syncthreads();   // all waves' gh reads of Ax complete before in-place write

  // GRU epilogue in-register. jf = this lane's feature; x_old from LDS.
  int jf = w*32 + lrow;
  float bi0 = b_ih[jf],     bh0 = b_hh[jf];
  float bi1 = b_ih[128+jf], bh1 = b_hh[128+jf];
  float bi2 = b_ih[256+jf], bh2 = b_hh[256+jf];
  float mb[3][3];
  #pragma unroll
  for(int t=0;t<3;t++){
    mb[t][0] = mbp[t*384 + jf];
    mb[t][1] = mbp[t*384 + 128 + jf];
    mb[t][2] = mbp[t*384 + 256 + jf];
  }
  int rq4 = 4*q;
  #pragma unroll
  for(int r=0;r<16;r++){
    int gl = (r&3) + 8*(r>>2) + rq4;          // local row 0..31
    float d0 = Dg[gl*3], d1 = Dg[gl*3+1], d2 = Dg[gl*3+2];
    float g0 = (float)gip[0][r>>1][r&1];
    float g1 = (float)gip[1][r>>1][r&1];
    float g2 = (float)gip[2][r>>1][r&1];
    float ir  = g0 + bi0 + d0*mb[0][0] + d1*mb[1][0] + d2*mb[2][0];
    float iz  = g1 + bi1 + d0*mb[0][1] + d1*mb[1][1] + d2*mb[2][1];
    float in_ = g2 + bi2 + d0*mb[0][2] + d1*mb[1][2] + d2*mb[2][2];
    float hr  = agh[0][r] + bh0;
    float hz  = agh[1][r] + bh1;
    float hn  = agh[2][r] + bh2;
    float rg = sigf(ir + hr);
    float zg = sigf(iz + hz);
    float nn = tanhf_fast(in_ + rg*hn);
    float xo = (float)Ax[gl*XSTR + jf];
    Ax[gl*XSTR + jf] = (f16)((1.f - zg)*nn + zg*xo);   // in-place, own slot
  }
  __syncthreads();
  // coalesced writeback from Ax
  #pragma unroll
  for(int p=0;p<2;p++){
    int ch = tid + p*256;
    int row = ch>>4, c8 = (ch&15)*8;
    int gr = row0 + row;
    if(gr < M)
      *(v8hf*)(xb_new + (size_t)gr*128 + c8) = *(const v8hf*)&Ax[row*XSTR + c8];
  }
}

__device__ __forceinline__ int lb_batch(const int* __restrict__ batch, int N, int g){
  int lo=0, hi=N;
  while(lo<hi){ int mid=(lo+hi)>>1; if(batch[mid]<g) lo=mid+1; else hi=mid; }
  return lo;
}

__global__ void k_pool2(const f16* __restrict__ xb, const int* __restrict__ batch,
                        float* __restrict__ pooled, int N){
  int g = blockIdx.x, slice = blockIdx.y;
  int j = threadIdx.x;
  int lo = lb_batch(batch,N,g), hi = lb_batch(batch,N,g+1);
  float acc = 0.f;
  for(int r=lo+slice; r<hi; r+=32) acc += (float)xb[(size_t)r*128 + j];
  atomicAdd(&pooled[g*128+j], acc);
}

__global__ void k_head(const float* __restrict__ pooled, const int* __restrict__ batch, int N,
                       const float* __restrict__ W1, const float* __restrict__ b1,
                       const float* __restrict__ W2, const float* __restrict__ b2,
                       float* __restrict__ out){
  int g = blockIdx.x; int j = threadIdx.x;
  __shared__ float p[128];
  __shared__ float red[128];
  int lo = lb_batch(batch,N,g), hi = lb_batch(batch,N,g+1);
  float c = (float)(hi-lo); if(c < 1.f) c = 1.f;
  p[j] = pooled[g*128+j] / c;
  __syncthreads();
  float acc = b1[j];
  #pragma unroll 4
  for(int i=0;i<128;i++) acc += W1[j*128+i]*p[i];
  float v = (acc>0.f?acc:0.f) * W2[j];
  red[j] = v; __syncthreads();
  for(int s=64;s>0;s>>=1){ if(j<s) red[j]+=red[j+s]; __syncthreads(); }
  if(j==0) out[g] = red[0] + b2[0];
}

extern "C" void kernel_launch(void* const* d_in, const int* in_sizes, int n_in,
                              void* d_out, int out_size, void* d_ws, size_t ws_size,
                              hipStream_t stream){
  const int*   x_type    = (const int*)d_in[0];
  const int*   x_tok     = (const int*)d_in[1];
  const float* x_small   = (const float*)d_in[2];
  const int*   edge_index= (const int*)d_in[3];
  const int*   edge_type = (const int*)d_in[4];
  const int*   batch     = (const int*)d_in[5];
  const float* type_emb  = (const float*)d_in[6];
  const float* tok_emb   = (const float*)d_in[7];
  const float* msg_W     = (const float*)d_in[8];
  const float* msg_b     = (const float*)d_in[9];
  const float* W_ih      = (const float*)d_in[10];
  const float* W_hh      = (const float*)d_in[11];
  const float* b_ih      = (const float*)d_in[12];
  const float* b_hh      = (const float*)d_in[13];
  const float* pW1       = (const float*)d_in[14];
  const float* pb1       = (const float*)d_in[15];
  const float* pW2       = (const float*)d_in[16];
  const float* pb2       = (const float*)d_in[17];
  float* out = (float*)d_out;

  int N = in_sizes[0];
  int E = in_sizes[3]/2;
  const int* src = edge_index;
  const int* dst = edge_index + E;
  int n3 = 3*N;
  int nch = (n3+1023)/1024;

  char* w = (char*)d_ws;
  size_t off = 0;
  auto alloc = [&](size_t bytes)->char*{ char* p = w + off; off += (bytes + 511) & ~511ull; return p; };
  f16*   xb0    = (f16*)alloc((size_t)N*128*2);       // ping (25.6 MB)
  f16*   xb1    = (f16*)alloc((size_t)N*128*2);       // pong (25.6 MB)
  f16*   s      = (f16*)alloc((size_t)N*384*2);       // gathered sums (76.8 MB)
  int*   deg3   = (int*)alloc((size_t)n3*4);
  int*   part   = (int*)alloc((size_t)n3*4);
  int*   rp3    = (int*)alloc((size_t)(n3+1)*4);
  int*   cursor = (int*)alloc((size_t)n3*4);
  int*   pay    = (int*)alloc((size_t)E*4);
  int*   bsum   = (int*)alloc((size_t)nch*4);
  int*   carry  = (int*)alloc((size_t)nch*4);
  float* Wc     = (float*)alloc((size_t)147456*4);
  f16*   WpF    = (f16*)alloc((size_t)(GI_F+GH_F)*2);
  float* mbp    = (float*)alloc((size_t)1152*4);
  float* pooled = (float*)alloc(64*128*4);
  if(off > ws_size){
    k_diag<<<1,64,0,stream>>>(out, out_size, 1.0e6f + (float)(ws_size>>20));
    return;
  }

  const int tb = 256;
  hipMemsetAsync(deg3, 0, (size_t)n3*4, stream);
  k_wcomb   <<<576, 256, 0, stream>>>(W_ih, msg_W, Wc);
  k_mbp     <<<5, 256, 0, stream>>>(W_ih, msg_b, mbp);
  k_wprep   <<<(GI_F+GH_F+255)/256, 256, 0, stream>>>(Wc, W_hh, WpF);
  k_hist3   <<<(E+tb-1)/tb, tb, 0, stream>>>(dst, edge_type, deg3, E);
  k_scan1   <<<nch, 256, 0, stream>>>(deg3, n3, part, bsum);
  k_scan2   <<<1, 64, 0, stream>>>(bsum, nch, carry);
  k_finalize<<<(n3+tb-1)/tb, tb, 0, stream>>>(part, deg3, carry, n3, rp3, cursor);
  k_fill3   <<<(E+tb-1)/tb, tb, 0, stream>>>(src, dst, edge_type, cursor, pay, E);
  k_embed   <<<N, 128, 0, stream>>>(x_type, x_tok, x_small, type_emb, tok_emb, xb0, N);

  int nblk = (N+31)/32;
  f16* xin = xb0;
  f16* xout = xb1;
  for(int it=0; it<8; it++){
    k_gather3_d<<<(N+7)/8, 256, 0, stream>>>(xin, rp3, pay, s, N);
    k_mega2b   <<<nblk, 256, 0, stream>>>(xin, xout, s, WpF, deg3, mbp, b_ih, b_hh, N);
    f16* tmp = xin; xin = xout; xout = tmp;
  }
  // final state is in xin after the swap
  hipMemsetAsync(pooled, 0, 64*128*4, stream);
  k_pool2<<<dim3(64,32), 128, 0, stream>>>(xin, batch, pooled, N);
  k_head <<<64, 128, 0, stream>>>(pooled, batch, N, pW1, pb1, pW2, pb2, out);
}

// Round 9
// 1148.263 us; speedup vs baseline: 2.6932x; 1.0112x over previous
//
#include <hip/hip_runtime.h>
#include <stdint.h>

// GGNN round 23 (= r22 with compile fix: #pragma cannot follow '{' on one
// line; replaced with addv() helper). Gather at max vectorization: 4 nodes
// per wave (one per 16-lane quarter), v8hf 16B loads (16 lanes x 16B =
// 256B/row). Per loop iter 6 vmem instr serve 12 edges (r21: 6); stores
// halve. Total vmem ~1.05M -> ~0.68M (-35%). Divergence waste rises
// (max-of-4 quarters) but each instr does 2x work - r21's winning tradeoff.
// mega2b LOCKED (196-unified-reg core; r16/r18/r20 all spilled on edit).

typedef _Float16 f16;
typedef _Float16 v8hf __attribute__((ext_vector_type(8)));
typedef _Float16 v4hf __attribute__((ext_vector_type(4)));
typedef _Float16 v2hf __attribute__((ext_vector_type(2)));
typedef float    v16f __attribute__((ext_vector_type(16)));

#define GI_F 147456   // 12 tiles * 24 ks * 512
#define GH_F 49152    // 12 tiles *  8 ks * 512

__device__ __forceinline__ float sigf(float a){
  return __fdividef(1.0f, 1.0f + __expf(-a));
}
__device__ __forceinline__ float tanhf_fast(float a){
  return 1.0f - __fdividef(2.0f, __expf(2.0f*a) + 1.0f);
}
__device__ __forceinline__ void addv(float* a, v8hf u){
  #pragma unroll
  for(int j=0;j<8;j++) a[j] += (float)u[j];
}

__global__ void k_diag(float* out, int n, float v){
  int i = threadIdx.x; if(i<n) out[i] = v;
}

__global__ void k_embed(const int* __restrict__ xtype, const int* __restrict__ xtok,
                        const float* __restrict__ xsmall,
                        const float* __restrict__ temb, const float* __restrict__ kemb,
                        f16* __restrict__ xb, int N){
  int n = blockIdx.x; int j = threadIdx.x;
  if(n>=N) return;
  float v;
  if(j<32)       v = temb[xtype[n]*32 + j];
  else if(j<64)  v = kemb[xtok[n]*32 + (j-32)];
  else           v = xsmall[(size_t)n*64 + (j-64)];
  xb[(size_t)n*128 + j] = (f16)v;
}

// Wc[o2][K] = sum_k2 W_ih[o2,k2] * msg_W[K>>7][k2][K&127]
__global__ void k_wcomb(const float* __restrict__ W_ih, const float* __restrict__ msg_W,
                        float* __restrict__ Wc){
  int i = blockIdx.x*256 + threadIdx.x;
  if(i >= 147456) return;
  int o2 = i/384, K = i%384;
  const float* wr = W_ih + o2*128;
  const float* mc = msg_W + (K>>7)*16384 + (K&127);
  float acc = 0.f;
  #pragma unroll 4
  for(int k2=0;k2<128;k2++) acc += wr[k2]*mc[k2*128];
  Wc[i] = acc;
}

// mbp[t][o2] = sum_k2 W_ih[o2,k2]*msg_b[t,k2]
__global__ void k_mbp(const float* __restrict__ W_ih, const float* __restrict__ msg_b,
                      float* __restrict__ mbp){
  int i = blockIdx.x*256 + threadIdx.x;
  if(i >= 1152) return;
  int t = i/384, o2 = i%384;
  const float* wr = W_ih + o2*128;
  const float* mb = msg_b + t*128;
  float acc = 0.f;
  #pragma unroll 4
  for(int k2=0;k2<128;k2++) acc += wr[k2]*mb[k2];
  mbp[i] = acc;
}

// Pack weights f16, MFMA B-frag order: n = tile*32+(lane&31), k = ks*16+(lane>>5)*8+j
__global__ void k_wprep(const float* __restrict__ Wc, const float* __restrict__ W_hh,
                        f16* __restrict__ WpF){
  int i = blockIdx.x*256 + threadIdx.x;
  if(i >= GI_F + GH_F) return;
  float w; int lane, j;
  if(i < GI_F){
    int grp = i/512, rem = i%512;
    lane = rem/8; j = rem%8;
    int tile = grp/24, ks = grp%24;
    int n = tile*32 + (lane&31);
    int k = ks*16 + (lane>>5)*8 + j;
    w = Wc[n*384 + k];
  } else {
    int i2 = i - GI_F;
    int grp = i2/512, rem = i2%512;
    lane = rem/8; j = rem%8;
    int tile = grp/8, ks = grp%8;
    int n = tile*32 + (lane&31);
    int k = ks*16 + (lane>>5)*8 + j;
    w = W_hh[n*128 + k];
  }
  WpF[i] = (f16)w;
}

__global__ void k_hist3(const int* __restrict__ dst, const int* __restrict__ et,
                        int* __restrict__ deg3, int E){
  int e = blockIdx.x*blockDim.x + threadIdx.x;
  if(e<E) atomicAdd(&deg3[dst[e]*3 + et[e]], 1);
}

__global__ void k_scan1(const int* __restrict__ deg, int n, int* __restrict__ part, int* __restrict__ bsum){
  __shared__ int s[256];
  int t = threadIdx.x;
  int base = blockIdx.x*1024 + t*4;
  int v[4]; int sum=0;
  #pragma unroll
  for(int k=0;k<4;k++){ int i=base+k; int d=(i<n)?deg[i]:0; sum+=d; v[k]=sum; }
  s[t]=sum; __syncthreads();
  for(int off=1;off<256;off<<=1){
    int add = (t>=off)? s[t-off] : 0;
    __syncthreads();
    s[t]+=add;
    __syncthreads();
  }
  int excl = (t>0)? s[t-1] : 0;
  #pragma unroll
  for(int k=0;k<4;k++){ int i=base+k; if(i<n) part[i]=v[k]+excl; }
  if(t==255) bsum[blockIdx.x] = s[255];
}

__global__ void k_scan2(const int* __restrict__ bsum, int nb, int* __restrict__ carry){
  if(threadIdx.x==0 && blockIdx.x==0){
    int c=0;
    for(int b=0;b<nb;b++){ carry[b]=c; c+=bsum[b]; }
  }
}

__global__ void k_finalize(const int* __restrict__ part, const int* __restrict__ deg,
                           const int* __restrict__ carry, int n,
                           int* __restrict__ rowptr, int* __restrict__ cursor){
  int i = blockIdx.x*blockDim.x + threadIdx.x;
  if(i>=n) return;
  int incl = part[i] + carry[i>>10];
  rowptr[i+1] = incl;
  cursor[i] = incl - deg[i];
  if(i==0) rowptr[0]=0;
}

__global__ void k_fill3(const int* __restrict__ src, const int* __restrict__ dst,
                        const int* __restrict__ et, int* __restrict__ cursor,
                        int* __restrict__ pay, int E){
  int e = blockIdx.x*blockDim.x + threadIdx.x;
  if(e>=E) return;
  int pos = atomicAdd(&cursor[dst[e]*3 + et[e]], 1);
  pay[pos] = src[e];
}

// gather: 4 nodes per wave (one per 16-lane quarter), lane covers 8 f16
// cols via one v8hf 16B load (16 lanes x 16B = 256B/row). 3-stream flat
// split of each node's CSR range. One vmem instr serves 4 nodes' edges.
__global__ void k_gather3_e(const f16* __restrict__ xb, const int* __restrict__ rp3,
                            const int* __restrict__ pay, f16* __restrict__ s, int N){
  int tid = threadIdx.x;
  int lane = tid & 63;
  int h = lane >> 4;          // quarter = node select within wave
  int c8 = (lane & 15)*8;     // col base (f16 cols)
  int n = blockIdx.x*16 + (tid>>6)*4 + h;
  bool valid = (n < N);
  int nn = valid ? n : (N-1);
  int b = nn*3;
  int lo = rp3[b], e0 = rp3[b+1], e1 = rp3[b+2], hi = rp3[b+3];
  if(!valid){ lo = 0; e0 = 0; e1 = 0; hi = 0; }
  float a0[8] = {}, a1[8] = {}, a2[8] = {};
  int len = hi - lo;
  int t1 = lo + len/3;
  int t2 = lo + (2*len)/3;
  int iA = lo, iB = t1, iC = t2;
  while(iA < t1 && iB < t2 && iC < hi){
    int pA = pay[iA], pB = pay[iB], pC = pay[iC];
    v8hf uA = *(const v8hf*)&xb[(size_t)pA*128 + c8];
    v8hf uB = *(const v8hf*)&xb[(size_t)pB*128 + c8];
    v8hf uC = *(const v8hf*)&xb[(size_t)pC*128 + c8];
    if(iA < e0)      addv(a0, uA);
    else if(iA < e1) addv(a1, uA);
    else             addv(a2, uA);
    if(iB < e0)      addv(a0, uB);
    else if(iB < e1) addv(a1, uB);
    else             addv(a2, uB);
    if(iC < e0)      addv(a0, uC);
    else if(iC < e1) addv(a1, uC);
    else             addv(a2, uC);
    iA++; iB++; iC++;
  }
  for(; iA < t1; iA++){
    v8hf u = *(const v8hf*)&xb[(size_t)pay[iA]*128 + c8];
    if(iA < e0)      addv(a0, u);
    else if(iA < e1) addv(a1, u);
    else             addv(a2, u);
  }
  for(; iB < t2; iB++){
    v8hf u = *(const v8hf*)&xb[(size_t)pay[iB]*128 + c8];
    if(iB < e0)      addv(a0, u);
    else if(iB < e1) addv(a1, u);
    else             addv(a2, u);
  }
  for(; iC < hi; iC++){
    v8hf u = *(const v8hf*)&xb[(size_t)pay[iC]*128 + c8];
    if(iC < e0)      addv(a0, u);
    else if(iC < e1) addv(a1, u);
    else             addv(a2, u);
  }
  if(valid){
    size_t o = (size_t)n*384 + c8;
    v8hf t;
    #pragma unroll
    for(int j=0;j<8;j++) t[j] = (f16)a0[j];
    *(v8hf*)&s[o] = t;
    #pragma unroll
    for(int j=0;j<8;j++) t[j] = (f16)a1[j];
    *(v8hf*)&s[o+128] = t;
    #pragma unroll
    for(int j=0;j<8;j++) t[j] = (f16)a2[j];
    *(v8hf*)&s[o+256] = t;
  }
}

// Fused gi+gh GEMM + GRU, f16 master. 32 rows/block, 256 threads (4 waves).
// Wave w col-tiles {w,w+4,w+8} => feature slice jf in [32w,32w+32) across all
// 3 gates for gi AND gh => GRU in-register. r19 core + barrier between the
// gh-phase LDS reads and the in-place Ax epilogue write. LOCKED.
#define SSTR 392   // 384+8
#define XSTR 136   // 128+8
__global__ __launch_bounds__(256,2) void k_mega2b(
    const f16* __restrict__ xb_old, f16* __restrict__ xb_new,
    const f16* __restrict__ s, const f16* __restrict__ WpF,
    const int* __restrict__ deg3, const float* __restrict__ mbp,
    const float* __restrict__ b_ih, const float* __restrict__ b_hh, int M)
{
  __shared__ f16 Ss[32*SSTR];   // 24.5 KB
  __shared__ f16 Ax[32*XSTR];   //  8.5 KB
  __shared__ float Dg[96];      // deg3 for this block's 32 rows
  int tid = threadIdx.x, lane = tid & 63, w = tid >> 6;
  int lrow = lane & 31, q = lane >> 5;
  int row0 = blockIdx.x * 32;

  // stage xb rows -> Ax: 512 chunks, 2/thread
  #pragma unroll
  for(int p=0;p<2;p++){
    int ch = tid + p*256;
    int row = ch>>4, c8 = (ch&15)*8;
    int gr = row0 + row; if(gr >= M) gr = M-1;
    *(v8hf*)&Ax[row*XSTR + c8] = *(const v8hf*)(xb_old + (size_t)gr*128 + c8);
  }
  // stage s rows -> Ss: 1536 chunks, 6/thread
  #pragma unroll
  for(int p=0;p<6;p++){
    int ch = tid + p*256;
    int row = ch/48, c8 = (ch%48)*8;
    int gr = row0 + row; if(gr >= M) gr = M-1;
    *(v8hf*)&Ss[row*SSTR + c8] = *(const v8hf*)(s + (size_t)gr*384 + c8);
  }
  // stage deg3 -> Dg
  if(tid < 96){
    int node = row0 + tid/3;
    Dg[tid] = (node < M) ? (float)deg3[node*3 + (tid - (tid/3)*3)] : 0.f;
  }
  __syncthreads();

  // ---- gi phase: K=384 over Ss ----
  v16f agi[3] = {};
  #pragma unroll
  for(int ks=0; ks<24; ks++){
    int kb = ks*16 + q*8;
    v8hf a0 = *(const v8hf*)&Ss[lrow*SSTR + kb];
    #pragma unroll
    for(int ct=0; ct<3; ct++){
      int tile = ct*4 + w;
      v8hf bh = *(const v8hf*)(WpF + (size_t)(tile*24 + ks)*512 + lane*8);
      agi[ct] = __builtin_amdgcn_mfma_f32_32x32x16_f16(a0, bh, agi[ct], 0,0,0);
    }
  }
  // pack agi -> f16 pairs in registers (frees 48 -> 24 regs; no cap => no spill)
  v2hf gip[3][8];
  #pragma unroll
  for(int ct=0; ct<3; ct++)
    #pragma unroll
    for(int rp=0; rp<8; rp++){
      v2hf t; t[0] = (f16)agi[ct][2*rp]; t[1] = (f16)agi[ct][2*rp+1];
      gip[ct][rp] = t;
    }

  // ---- gh phase: K=128 over Ax ----
  v16f agh[3] = {};
  #pragma unroll
  for(int ks=0; ks<8; ks++){
    int kb = ks*16 + q*8;
    v8hf a0 = *(const v8hf*)&Ax[lrow*XSTR + kb];
    #pragma unroll
    for(int ct=0; ct<3; ct++){
      int tile = ct*4 + w;
      v8hf bh = *(const v8hf*)(WpF + GI_F + (size_t)(tile*8 + ks)*512 + lane*8);
      agh[ct] = __builtin_amdgcn_mfma_f32_32x32x16_f16(a0, bh, agh[ct], 0,0,0);
    }
  }

  __syncthreads();   // all waves' gh reads of Ax complete before in-place write

  // GRU epilogue in-register. jf = this lane's feature; x_old from LDS.
  int jf = w*32 + lrow;
  float bi0 = b_ih[jf],     bh0 = b_hh[jf];
  float bi1 = b_ih[128+jf], bh1 = b_hh[128+jf];
  float bi2 = b_ih[256+jf], bh2 = b_hh[256+jf];
  float mb[3][3];
  #pragma unroll
  for(int t=0;t<3;t++){
    mb[t][0] = mbp[t*384 + jf];
    mb[t][1] = mbp[t*384 + 128 + jf];
    mb[t][2] = mbp[t*384 + 256 + jf];
  }
  int rq4 = 4*q;
  #pragma unroll
  for(int r=0;r<16;r++){
    int gl = (r&3) + 8*(r>>2) + rq4;          // local row 0..31
    float d0 = Dg[gl*3], d1 = Dg[gl*3+1], d2 = Dg[gl*3+2];
    float g0 = (float)gip[0][r>>1][r&1];
    float g1 = (float)gip[1][r>>1][r&1];
    float g2 = (float)gip[2][r>>1][r&1];
    float ir  = g0 + bi0 + d0*mb[0][0] + d1*mb[1][0] + d2*mb[2][0];
    float iz  = g1 + bi1 + d0*mb[0][1] + d1*mb[1][1] + d2*mb[2][1];
    float in_ = g2 + bi2 + d0*mb[0][2] + d1*mb[1][2] + d2*mb[2][2];
    float hr  = agh[0][r] + bh0;
    float hz  = agh[1][r] + bh1;
    float hn  = agh[2][r] + bh2;
    float rg = sigf(ir + hr);
    float zg = sigf(iz + hz);
    float nn = tanhf_fast(in_ + rg*hn);
    float xo = (float)Ax[gl*XSTR + jf];
    Ax[gl*XSTR + jf] = (f16)((1.f - zg)*nn + zg*xo);   // in-place, own slot
  }
  __syncthreads();
  // coalesced writeback from Ax
  #pragma unroll
  for(int p=0;p<2;p++){
    int ch = tid + p*256;
    int row = ch>>4, c8 = (ch&15)*8;
    int gr = row0 + row;
    if(gr < M)
      *(v8hf*)(xb_new + (size_t)gr*128 + c8) = *(const v8hf*)&Ax[row*XSTR + c8];
  }
}

__device__ __forceinline__ int lb_batch(const int* __restrict__ batch, int N, int g){
  int lo=0, hi=N;
  while(lo<hi){ int mid=(lo+hi)>>1; if(batch[mid]<g) lo=mid+1; else hi=mid; }
  return lo;
}

__global__ void k_pool2(const f16* __restrict__ xb, const int* __restrict__ batch,
                        float* __restrict__ pooled, int N){
  int g = blockIdx.x, slice = blockIdx.y;
  int j = threadIdx.x;
  int lo = lb_batch(batch,N,g), hi = lb_batch(batch,N,g+1);
  float acc = 0.f;
  for(int r=lo+slice; r<hi; r+=32) acc += (float)xb[(size_t)r*128 + j];
  atomicAdd(&pooled[g*128+j], acc);
}

__global__ void k_head(const float* __restrict__ pooled, const int* __restrict__ batch, int N,
                       const float* __restrict__ W1, const float* __restrict__ b1,
                       const float* __restrict__ W2, const float* __restrict__ b2,
                       float* __restrict__ out){
  int g = blockIdx.x; int j = threadIdx.x;
  __shared__ float p[128];
  __shared__ float red[128];
  int lo = lb_batch(batch,N,g), hi = lb_batch(batch,N,g+1);
  float c = (float)(hi-lo); if(c < 1.f) c = 1.f;
  p[j] = pooled[g*128+j] / c;
  __syncthreads();
  float acc = b1[j];
  #pragma unroll 4
  for(int i=0;i<128;i++) acc += W1[j*128+i]*p[i];
  float v = (acc>0.f?acc:0.f) * W2[j];
  red[j] = v; __syncthreads();
  for(int s=64;s>0;s>>=1){ if(j<s) red[j]+=red[j+s]; __syncthreads(); }
  if(j==0) out[g] = red[0] + b2[0];
}

extern "C" void kernel_launch(void* const* d_in, const int* in_sizes, int n_in,
                              void* d_out, int out_size, void* d_ws, size_t ws_size,
                              hipStream_t stream){
  const int*   x_type    = (const int*)d_in[0];
  const int*   x_tok     = (const int*)d_in[1];
  const float* x_small   = (const float*)d_in[2];
  const int*   edge_index= (const int*)d_in[3];
  const int*   edge_type = (const int*)d_in[4];
  const int*   batch     = (const int*)d_in[5];
  const float* type_emb  = (const float*)d_in[6];
  const float* tok_emb   = (const float*)d_in[7];
  const float* msg_W     = (const float*)d_in[8];
  const float* msg_b     = (const float*)d_in[9];
  const float* W_ih      = (const float*)d_in[10];
  const float* W_hh      = (const float*)d_in[11];
  const float* b_ih      = (const float*)d_in[12];
  const float* b_hh      = (const float*)d_in[13];
  const float* pW1       = (const float*)d_in[14];
  const float* pb1       = (const float*)d_in[15];
  const float* pW2       = (const float*)d_in[16];
  const float* pb2       = (const float*)d_in[17];
  float* out = (float*)d_out;

  int N = in_sizes[0];
  int E = in_sizes[3]/2;
  const int* src = edge_index;
  const int* dst = edge_index + E;
  int n3 = 3*N;
  int nch = (n3+1023)/1024;

  char* w = (char*)d_ws;
  size_t off = 0;
  auto alloc = [&](size_t bytes)->char*{ char* p = w + off; off += (bytes + 511) & ~511ull; return p; };
  f16*   xb0    = (f16*)alloc((size_t)N*128*2);       // ping (25.6 MB)
  f16*   xb1    = (f16*)alloc((size_t)N*128*2);       // pong (25.6 MB)
  f16*   s      = (f16*)alloc((size_t)N*384*2);       // gathered sums (76.8 MB)
  int*   deg3   = (int*)alloc((size_t)n3*4);
  int*   part   = (int*)alloc((size_t)n3*4);
  int*   rp3    = (int*)alloc((size_t)(n3+1)*4);
  int*   cursor = (int*)alloc((size_t)n3*4);
  int*   pay    = (int*)alloc((size_t)E*4);
  int*   bsum   = (int*)alloc((size_t)nch*4);
  int*   carry  = (int*)alloc((size_t)nch*4);
  float* Wc     = (float*)alloc((size_t)147456*4);
  f16*   WpF    = (f16*)alloc((size_t)(GI_F+GH_F)*2);
  float* mbp    = (float*)alloc((size_t)1152*4);
  float* pooled = (float*)alloc(64*128*4);
  if(off > ws_size){
    k_diag<<<1,64,0,stream>>>(out, out_size, 1.0e6f + (float)(ws_size>>20));
    return;
  }

  const int tb = 256;
  hipMemsetAsync(deg3, 0, (size_t)n3*4, stream);
  k_wcomb   <<<576, 256, 0, stream>>>(W_ih, msg_W, Wc);
  k_mbp     <<<5, 256, 0, stream>>>(W_ih, msg_b, mbp);
  k_wprep   <<<(GI_F+GH_F+255)/256, 256, 0, stream>>>(Wc, W_hh, WpF);
  k_hist3   <<<(E+tb-1)/tb, tb, 0, stream>>>(dst, edge_type, deg3, E);
  k_scan1   <<<nch, 256, 0, stream>>>(deg3, n3, part, bsum);
  k_scan2   <<<1, 64, 0, stream>>>(bsum, nch, carry);
  k_finalize<<<(n3+tb-1)/tb, tb, 0, stream>>>(part, deg3, carry, n3, rp3, cursor);
  k_fill3   <<<(E+tb-1)/tb, tb, 0, stream>>>(src, dst, edge_type, cursor, pay, E);
  k_embed   <<<N, 128, 0, stream>>>(x_type, x_tok, x_small, type_emb, tok_emb, xb0, N);

  int nblk = (N+31)/32;
  f16* xin = xb0;
  f16* xout = xb1;
  for(int it=0; it<8; it++){
    k_gather3_e<<<(N+15)/16, 256, 0, stream>>>(xin, rp3, pay, s, N);
    k_mega2b   <<<nblk, 256, 0, stream>>>(xin, xout, s, WpF, deg3, mbp, b_ih, b_hh, N);
    f16* tmp = xin; xin = xout; xout = tmp;
  }
  // final state is in xin after the swap
  hipMemsetAsync(pooled, 0, 64*128*4, stream);
  k_pool2<<<dim3(64,32), 128, 0, stream>>>(xin, batch, pooled, N);
  k_head <<<64, 128, 0, stream>>>(pooled, batch, N, pW1, pb1, pW2, pb2, out);
}

// Round 10
// 1135.213 us; speedup vs baseline: 2.7241x; 1.0115x over previous
//
#include <hip/hip_runtime.h>
#include <stdint.h>

// GGNN round 24: gather VALU cut. r23 showed the VMEM axis exhausted
// (4-node variant -1us); re-derived budget: gather is VALU-issue bound
// (~24 cvt + up to 72 masked adds + 64-bit addr math per iter ~= 45us).
// Fix: (1) f16 packed accumulation - v8hf acc += u -> 4 v_pk_add_f16
// per 8 cols, no cvts (s is already f16-rounded at output today; extra
// error ~sqrt(deg)*eps, absmax expected ~1e-4; GAMBLE on tolerance,
// revert to f32-acc if failed). (2) pay stores byte offsets (src*256)
// -> kills the 32x32->64 mul per row load.
// mega2b LOCKED (196-unified-reg core; r16/r18/r20 all spilled on edit).

typedef _Float16 f16;
typedef _Float16 v8hf __attribute__((ext_vector_type(8)));
typedef _Float16 v2hf __attribute__((ext_vector_type(2)));
typedef float    v16f __attribute__((ext_vector_type(16)));

#define GI_F 147456   // 12 tiles * 24 ks * 512
#define GH_F 49152    // 12 tiles *  8 ks * 512

__device__ __forceinline__ float sigf(float a){
  return __fdividef(1.0f, 1.0f + __expf(-a));
}
__device__ __forceinline__ float tanhf_fast(float a){
  return 1.0f - __fdividef(2.0f, __expf(2.0f*a) + 1.0f);
}

__global__ void k_diag(float* out, int n, float v){
  int i = threadIdx.x; if(i<n) out[i] = v;
}

__global__ void k_embed(const int* __restrict__ xtype, const int* __restrict__ xtok,
                        const float* __restrict__ xsmall,
                        const float* __restrict__ temb, const float* __restrict__ kemb,
                        f16* __restrict__ xb, int N){
  int n = blockIdx.x; int j = threadIdx.x;
  if(n>=N) return;
  float v;
  if(j<32)       v = temb[xtype[n]*32 + j];
  else if(j<64)  v = kemb[xtok[n]*32 + (j-32)];
  else           v = xsmall[(size_t)n*64 + (j-64)];
  xb[(size_t)n*128 + j] = (f16)v;
}

// Wc[o2][K] = sum_k2 W_ih[o2,k2] * msg_W[K>>7][k2][K&127]
__global__ void k_wcomb(const float* __restrict__ W_ih, const float* __restrict__ msg_W,
                        float* __restrict__ Wc){
  int i = blockIdx.x*256 + threadIdx.x;
  if(i >= 147456) return;
  int o2 = i/384, K = i%384;
  const float* wr = W_ih + o2*128;
  const float* mc = msg_W + (K>>7)*16384 + (K&127);
  float acc = 0.f;
  #pragma unroll 4
  for(int k2=0;k2<128;k2++) acc += wr[k2]*mc[k2*128];
  Wc[i] = acc;
}

// mbp[t][o2] = sum_k2 W_ih[o2,k2]*msg_b[t,k2]
__global__ void k_mbp(const float* __restrict__ W_ih, const float* __restrict__ msg_b,
                      float* __restrict__ mbp){
  int i = blockIdx.x*256 + threadIdx.x;
  if(i >= 1152) return;
  int t = i/384, o2 = i%384;
  const float* wr = W_ih + o2*128;
  const float* mb = msg_b + t*128;
  float acc = 0.f;
  #pragma unroll 4
  for(int k2=0;k2<128;k2++) acc += wr[k2]*mb[k2];
  mbp[i] = acc;
}

// Pack weights f16, MFMA B-frag order: n = tile*32+(lane&31), k = ks*16+(lane>>5)*8+j
__global__ void k_wprep(const float* __restrict__ Wc, const float* __restrict__ W_hh,
                        f16* __restrict__ WpF){
  int i = blockIdx.x*256 + threadIdx.x;
  if(i >= GI_F + GH_F) return;
  float w; int lane, j;
  if(i < GI_F){
    int grp = i/512, rem = i%512;
    lane = rem/8; j = rem%8;
    int tile = grp/24, ks = grp%24;
    int n = tile*32 + (lane&31);
    int k = ks*16 + (lane>>5)*8 + j;
    w = Wc[n*384 + k];
  } else {
    int i2 = i - GI_F;
    int grp = i2/512, rem = i2%512;
    lane = rem/8; j = rem%8;
    int tile = grp/8, ks = grp%8;
    int n = tile*32 + (lane&31);
    int k = ks*16 + (lane>>5)*8 + j;
    w = W_hh[n*128 + k];
  }
  WpF[i] = (f16)w;
}

__global__ void k_hist3(const int* __restrict__ dst, const int* __restrict__ et,
                        int* __restrict__ deg3, int E){
  int e = blockIdx.x*blockDim.x + threadIdx.x;
  if(e<E) atomicAdd(&deg3[dst[e]*3 + et[e]], 1);
}

__global__ void k_scan1(const int* __restrict__ deg, int n, int* __restrict__ part, int* __restrict__ bsum){
  __shared__ int s[256];
  int t = threadIdx.x;
  int base = blockIdx.x*1024 + t*4;
  int v[4]; int sum=0;
  #pragma unroll
  for(int k=0;k<4;k++){ int i=base+k; int d=(i<n)?deg[i]:0; sum+=d; v[k]=sum; }
  s[t]=sum; __syncthreads();
  for(int off=1;off<256;off<<=1){
    int add = (t>=off)? s[t-off] : 0;
    __syncthreads();
    s[t]+=add;
    __syncthreads();
  }
  int excl = (t>0)? s[t-1] : 0;
  #pragma unroll
  for(int k=0;k<4;k++){ int i=base+k; if(i<n) part[i]=v[k]+excl; }
  if(t==255) bsum[blockIdx.x] = s[255];
}

__global__ void k_scan2(const int* __restrict__ bsum, int nb, int* __restrict__ carry){
  if(threadIdx.x==0 && blockIdx.x==0){
    int c=0;
    for(int b=0;b<nb;b++){ carry[b]=c; c+=bsum[b]; }
  }
}

__global__ void k_finalize(const int* __restrict__ part, const int* __restrict__ deg,
                           const int* __restrict__ carry, int n,
                           int* __restrict__ rowptr, int* __restrict__ cursor){
  int i = blockIdx.x*blockDim.x + threadIdx.x;
  if(i>=n) return;
  int incl = part[i] + carry[i>>10];
  rowptr[i+1] = incl;
  cursor[i] = incl - deg[i];
  if(i==0) rowptr[0]=0;
}

// pay stores BYTE offsets of source rows (src*256); max 25.6MB < 2^31.
__global__ void k_fill3(const int* __restrict__ src, const int* __restrict__ dst,
                        const int* __restrict__ et, int* __restrict__ cursor,
                        int* __restrict__ pay, int E){
  int e = blockIdx.x*blockDim.x + threadIdx.x;
  if(e>=E) return;
  int pos = atomicAdd(&cursor[dst[e]*3 + et[e]], 1);
  pay[pos] = src[e] << 8;     // byte offset: 128 f16 * 2B = 256B/row
}

// gather: 4 nodes per wave (one per 16-lane quarter), lane covers 8 f16
// cols via one v8hf 16B load. f16 packed accumulation (v_pk_add_f16),
// byte-offset pay -> no mul in address path.
__global__ void k_gather3_f(const f16* __restrict__ xb, const int* __restrict__ rp3,
                            const int* __restrict__ pay, f16* __restrict__ s, int N){
  int tid = threadIdx.x;
  int lane = tid & 63;
  int h = lane >> 4;          // quarter = node select within wave
  int c8b = (lane & 15)*16;   // col byte offset within row
  const char* xbb = (const char*)xb;
  int n = blockIdx.x*16 + (tid>>6)*4 + h;
  bool valid = (n < N);
  int nn = valid ? n : (N-1);
  int b = nn*3;
  int lo = rp3[b], e0 = rp3[b+1], e1 = rp3[b+2], hi = rp3[b+3];
  if(!valid){ lo = 0; e0 = 0; e1 = 0; hi = 0; }
  v8hf a0 = {}, a1 = {}, a2 = {};
  int len = hi - lo;
  int t1 = lo + len/3;
  int t2 = lo + (2*len)/3;
  int iA = lo, iB = t1, iC = t2;
  while(iA < t1 && iB < t2 && iC < hi){
    int pA = pay[iA], pB = pay[iB], pC = pay[iC];
    v8hf uA = *(const v8hf*)(xbb + pA + c8b);
    v8hf uB = *(const v8hf*)(xbb + pB + c8b);
    v8hf uC = *(const v8hf*)(xbb + pC + c8b);
    if(iA < e0)      a0 += uA;
    else if(iA < e1) a1 += uA;
    else             a2 += uA;
    if(iB < e0)      a0 += uB;
    else if(iB < e1) a1 += uB;
    else             a2 += uB;
    if(iC < e0)      a0 += uC;
    else if(iC < e1) a1 += uC;
    else             a2 += uC;
    iA++; iB++; iC++;
  }
  for(; iA < t1; iA++){
    v8hf u = *(const v8hf*)(xbb + pay[iA] + c8b);
    if(iA < e0)      a0 += u;
    else if(iA < e1) a1 += u;
    else             a2 += u;
  }
  for(; iB < t2; iB++){
    v8hf u = *(const v8hf*)(xbb + pay[iB] + c8b);
    if(iB < e0)      a0 += u;
    else if(iB < e1) a1 += u;
    else             a2 += u;
  }
  for(; iC < hi; iC++){
    v8hf u = *(const v8hf*)(xbb + pay[iC] + c8b);
    if(iC < e0)      a0 += u;
    else if(iC < e1) a1 += u;
    else             a2 += u;
  }
  if(valid){
    char* sb = (char*)s + (size_t)n*768 + c8b;
    *(v8hf*)(sb)       = a0;
    *(v8hf*)(sb + 256) = a1;
    *(v8hf*)(sb + 512) = a2;
  }
}

// Fused gi+gh GEMM + GRU, f16 master. 32 rows/block, 256 threads (4 waves).
// Wave w col-tiles {w,w+4,w+8} => feature slice jf in [32w,32w+32) across all
// 3 gates for gi AND gh => GRU in-register. r19 core + barrier between the
// gh-phase LDS reads and the in-place Ax epilogue write. LOCKED.
#define SSTR 392   // 384+8
#define XSTR 136   // 128+8
__global__ __launch_bounds__(256,2) void k_mega2b(
    const f16* __restrict__ xb_old, f16* __restrict__ xb_new,
    const f16* __restrict__ s, const f16* __restrict__ WpF,
    const int* __restrict__ deg3, const float* __restrict__ mbp,
    const float* __restrict__ b_ih, const float* __restrict__ b_hh, int M)
{
  __shared__ f16 Ss[32*SSTR];   // 24.5 KB
  __shared__ f16 Ax[32*XSTR];   //  8.5 KB
  __shared__ float Dg[96];      // deg3 for this block's 32 rows
  int tid = threadIdx.x, lane = tid & 63, w = tid >> 6;
  int lrow = lane & 31, q = lane >> 5;
  int row0 = blockIdx.x * 32;

  // stage xb rows -> Ax: 512 chunks, 2/thread
  #pragma unroll
  for(int p=0;p<2;p++){
    int ch = tid + p*256;
    int row = ch>>4, c8 = (ch&15)*8;
    int gr = row0 + row; if(gr >= M) gr = M-1;
    *(v8hf*)&Ax[row*XSTR + c8] = *(const v8hf*)(xb_old + (size_t)gr*128 + c8);
  }
  // stage s rows -> Ss: 1536 chunks, 6/thread
  #pragma unroll
  for(int p=0;p<6;p++){
    int ch = tid + p*256;
    int row = ch/48, c8 = (ch%48)*8;
    int gr = row0 + row; if(gr >= M) gr = M-1;
    *(v8hf*)&Ss[row*SSTR + c8] = *(const v8hf*)(s + (size_t)gr*384 + c8);
  }
  // stage deg3 -> Dg
  if(tid < 96){
    int node = row0 + tid/3;
    Dg[tid] = (node < M) ? (float)deg3[node*3 + (tid - (tid/3)*3)] : 0.f;
  }
  __syncthreads();

  // ---- gi phase: K=384 over Ss ----
  v16f agi[3] = {};
  #pragma unroll
  for(int ks=0; ks<24; ks++){
    int kb = ks*16 + q*8;
    v8hf a0 = *(const v8hf*)&Ss[lrow*SSTR + kb];
    #pragma unroll
    for(int ct=0; ct<3; ct++){
      int tile = ct*4 + w;
      v8hf bh = *(const v8hf*)(WpF + (size_t)(tile*24 + ks)*512 + lane*8);
      agi[ct] = __builtin_amdgcn_mfma_f32_32x32x16_f16(a0, bh, agi[ct], 0,0,0);
    }
  }
  // pack agi -> f16 pairs in registers (frees 48 -> 24 regs; no cap => no spill)
  v2hf gip[3][8];
  #pragma unroll
  for(int ct=0; ct<3; ct++)
    #pragma unroll
    for(int rp=0; rp<8; rp++){
      v2hf t; t[0] = (f16)agi[ct][2*rp]; t[1] = (f16)agi[ct][2*rp+1];
      gip[ct][rp] = t;
    }

  // ---- gh phase: K=128 over Ax ----
  v16f agh[3] = {};
  #pragma unroll
  for(int ks=0; ks<8; ks++){
    int kb = ks*16 + q*8;
    v8hf a0 = *(const v8hf*)&Ax[lrow*XSTR + kb];
    #pragma unroll
    for(int ct=0; ct<3; ct++){
      int tile = ct*4 + w;
      v8hf bh = *(const v8hf*)(WpF + GI_F + (size_t)(tile*8 + ks)*512 + lane*8);
      agh[ct] = __builtin_amdgcn_mfma_f32_32x32x16_f16(a0, bh, agh[ct], 0,0,0);
    }
  }

  __syncthreads();   // all waves' gh reads of Ax complete before in-place write

  // GRU epilogue in-register. jf = this lane's feature; x_old from LDS.
  int jf = w*32 + lrow;
  float bi0 = b_ih[jf],     bh0 = b_hh[jf];
  float bi1 = b_ih[128+jf], bh1 = b_hh[128+jf];
  float bi2 = b_ih[256+jf], bh2 = b_hh[256+jf];
  float mb[3][3];
  #pragma unroll
  for(int t=0;t<3;t++){
    mb[t][0] = mbp[t*384 + jf];
    mb[t][1] = mbp[t*384 + 128 + jf];
    mb[t][2] = mbp[t*384 + 256 + jf];
  }
  int rq4 = 4*q;
  #pragma unroll
  for(int r=0;r<16;r++){
    int gl = (r&3) + 8*(r>>2) + rq4;          // local row 0..31
    float d0 = Dg[gl*3], d1 = Dg[gl*3+1], d2 = Dg[gl*3+2];
    float g0 = (float)gip[0][r>>1][r&1];
    float g1 = (float)gip[1][r>>1][r&1];
    float g2 = (float)gip[2][r>>1][r&1];
    float ir  = g0 + bi0 + d0*mb[0][0] + d1*mb[1][0] + d2*mb[2][0];
    float iz  = g1 + bi1 + d0*mb[0][1] + d1*mb[1][1] + d2*mb[2][1];
    float in_ = g2 + bi2 + d0*mb[0][2] + d1*mb[1][2] + d2*mb[2][2];
    float hr  = agh[0][r] + bh0;
    float hz  = agh[1][r] + bh1;
    float hn  = agh[2][r] + bh2;
    float rg = sigf(ir + hr);
    float zg = sigf(iz + hz);
    float nn = tanhf_fast(in_ + rg*hn);
    float xo = (float)Ax[gl*XSTR + jf];
    Ax[gl*XSTR + jf] = (f16)((1.f - zg)*nn + zg*xo);   // in-place, own slot
  }
  __syncthreads();
  // coalesced writeback from Ax
  #pragma unroll
  for(int p=0;p<2;p++){
    int ch = tid + p*256;
    int row = ch>>4, c8 = (ch&15)*8;
    int gr = row0 + row;
    if(gr < M)
      *(v8hf*)(xb_new + (size_t)gr*128 + c8) = *(const v8hf*)&Ax[row*XSTR + c8];
  }
}

__device__ __forceinline__ int lb_batch(const int* __restrict__ batch, int N, int g){
  int lo=0, hi=N;
  while(lo<hi){ int mid=(lo+hi)>>1; if(batch[mid]<g) lo=mid+1; else hi=mid; }
  return lo;
}

__global__ void k_pool2(const f16* __restrict__ xb, const int* __restrict__ batch,
                        float* __restrict__ pooled, int N){
  int g = blockIdx.x, slice = blockIdx.y;
  int j = threadIdx.x;
  int lo = lb_batch(batch,N,g), hi = lb_batch(batch,N,g+1);
  float acc = 0.f;
  for(int r=lo+slice; r<hi; r+=32) acc += (float)xb[(size_t)r*128 + j];
  atomicAdd(&pooled[g*128+j], acc);
}

__global__ void k_head(const float* __restrict__ pooled, const int* __restrict__ batch, int N,
                       const float* __restrict__ W1, const float* __restrict__ b1,
                       const float* __restrict__ W2, const float* __restrict__ b2,
                       float* __restrict__ out){
  int g = blockIdx.x; int j = threadIdx.x;
  __shared__ float p[128];
  __shared__ float red[128];
  int lo = lb_batch(batch,N,g), hi = lb_batch(batch,N,g+1);
  float c = (float)(hi-lo); if(c < 1.f) c = 1.f;
  p[j] = pooled[g*128+j] / c;
  __syncthreads();
  float acc = b1[j];
  #pragma unroll 4
  for(int i=0;i<128;i++) acc += W1[j*128+i]*p[i];
  float v = (acc>0.f?acc:0.f) * W2[j];
  red[j] = v; __syncthreads();
  for(int s=64;s>0;s>>=1){ if(j<s) red[j]+=red[j+s]; __syncthreads(); }
  if(j==0) out[g] = red[0] + b2[0];
}

extern "C" void kernel_launch(void* const* d_in, const int* in_sizes, int n_in,
                              void* d_out, int out_size, void* d_ws, size_t ws_size,
                              hipStream_t stream){
  const int*   x_type    = (const int*)d_in[0];
  const int*   x_tok     = (const int*)d_in[1];
  const float* x_small   = (const float*)d_in[2];
  const int*   edge_index= (const int*)d_in[3];
  const int*   edge_type = (const int*)d_in[4];
  const int*   batch     = (const int*)d_in[5];
  const float* type_emb  = (const float*)d_in[6];
  const float* tok_emb   = (const float*)d_in[7];
  const float* msg_W     = (const float*)d_in[8];
  const float* msg_b     = (const float*)d_in[9];
  const float* W_ih      = (const float*)d_in[10];
  const float* W_hh      = (const float*)d_in[11];
  const float* b_ih      = (const float*)d_in[12];
  const float* b_hh      = (const float*)d_in[13];
  const float* pW1       = (const float*)d_in[14];
  const float* pb1       = (const float*)d_in[15];
  const float* pW2       = (const float*)d_in[16];
  const float* pb2       = (const float*)d_in[17];
  float* out = (float*)d_out;

  int N = in_sizes[0];
  int E = in_sizes[3]/2;
  const int* src = edge_index;
  const int* dst = edge_index + E;
  int n3 = 3*N;
  int nch = (n3+1023)/1024;

  char* w = (char*)d_ws;
  size_t off = 0;
  auto alloc = [&](size_t bytes)->char*{ char* p = w + off; off += (bytes + 511) & ~511ull; return p; };
  f16*   xb0    = (f16*)alloc((size_t)N*128*2);       // ping (25.6 MB)
  f16*   xb1    = (f16*)alloc((size_t)N*128*2);       // pong (25.6 MB)
  f16*   s      = (f16*)alloc((size_t)N*384*2);       // gathered sums (76.8 MB)
  int*   deg3   = (int*)alloc((size_t)n3*4);
  int*   part   = (int*)alloc((size_t)n3*4);
  int*   rp3    = (int*)alloc((size_t)(n3+1)*4);
  int*   cursor = (int*)alloc((size_t)n3*4);
  int*   pay    = (int*)alloc((size_t)E*4);
  int*   bsum   = (int*)alloc((size_t)nch*4);
  int*   carry  = (int*)alloc((size_t)nch*4);
  float* Wc     = (float*)alloc((size_t)147456*4);
  f16*   WpF    = (f16*)alloc((size_t)(GI_F+GH_F)*2);
  float* mbp    = (float*)alloc((size_t)1152*4);
  float* pooled = (float*)alloc(64*128*4);
  if(off > ws_size){
    k_diag<<<1,64,0,stream>>>(out, out_size, 1.0e6f + (float)(ws_size>>20));
    return;
  }

  const int tb = 256;
  hipMemsetAsync(deg3, 0, (size_t)n3*4, stream);
  k_wcomb   <<<576, 256, 0, stream>>>(W_ih, msg_W, Wc);
  k_mbp     <<<5, 256, 0, stream>>>(W_ih, msg_b, mbp);
  k_wprep   <<<(GI_F+GH_F+255)/256, 256, 0, stream>>>(Wc, W_hh, WpF);
  k_hist3   <<<(E+tb-1)/tb, tb, 0, stream>>>(dst, edge_type, deg3, E);
  k_scan1   <<<nch, 256, 0, stream>>>(deg3, n3, part, bsum);
  k_scan2   <<<1, 64, 0, stream>>>(bsum, nch, carry);
  k_finalize<<<(n3+tb-1)/tb, tb, 0, stream>>>(part, deg3, carry, n3, rp3, cursor);
  k_fill3   <<<(E+tb-1)/tb, tb, 0, stream>>>(src, dst, edge_type, cursor, pay, E);
  k_embed   <<<N, 128, 0, stream>>>(x_type, x_tok, x_small, type_emb, tok_emb, xb0, N);

  int nblk = (N+31)/32;
  f16* xin = xb0;
  f16* xout = xb1;
  for(int it=0; it<8; it++){
    k_gather3_f<<<(N+15)/16, 256, 0, stream>>>(xin, rp3, pay, s, N);
    k_mega2b   <<<nblk, 256, 0, stream>>>(xin, xout, s, WpF, deg3, mbp, b_ih, b_hh, N);
    f16* tmp = xin; xin = xout; xout = tmp;
  }
  // final state is in xin after the swap
  hipMemsetAsync(pooled, 0, 64*128*4, stream);
  k_pool2<<<dim3(64,32), 128, 0, stream>>>(xin, batch, pooled, N);
  k_head <<<64, 128, 0, stream>>>(pooled, batch, N, pW1, pb1, pW2, pb2, out);
}

// Round 11
// 1089.757 us; speedup vs baseline: 2.8377x; 1.0417x over previous
//
#include <hip/hip_runtime.h>
#include <stdint.h>

// GGNN round 25: break the 96-AGPR occupancy pin STRUCTURALLY. The GRU's
// r,z gates only use gi+gh SUMMED -> continue gh MFMAs into the same
// accumulators (MFMA C-op is free addition); only the n gate (rg*hn)
// needs gi,gh separate -> pack just acc2 (8 v2hf) + one fresh 16-reg gh-n
// acc. Peak acc = 48 AGPR at all times (was 96 disjoint) -> unified ~150,
// fits (256,3)'s 170 cap with slack. Unlike r16 (capped unchanged live
// set), r18 (fat cross-gate state), r20 (added prefetch state), here the
// live set genuinely shrinks. Bonus: r/z gi+gh summed in f32 MFMA
// precision (better than old f16 pack), pack VALU cut 2/3.
// No-spill check: WRITE_SIZE must stay 25.0MB. Revert to r24 if not.
// gather3_f at its L2/L3 random-access floor (~44us/iter) - closed.

typedef _Float16 f16;
typedef _Float16 v8hf __attribute__((ext_vector_type(8)));
typedef _Float16 v2hf __attribute__((ext_vector_type(2)));
typedef float    v16f __attribute__((ext_vector_type(16)));

#define GI_F 147456   // 12 tiles * 24 ks * 512
#define GH_F 49152    // 12 tiles *  8 ks * 512

__device__ __forceinline__ float sigf(float a){
  return __fdividef(1.0f, 1.0f + __expf(-a));
}
__device__ __forceinline__ float tanhf_fast(float a){
  return 1.0f - __fdividef(2.0f, __expf(2.0f*a) + 1.0f);
}

__global__ void k_diag(float* out, int n, float v){
  int i = threadIdx.x; if(i<n) out[i] = v;
}

__global__ void k_embed(const int* __restrict__ xtype, const int* __restrict__ xtok,
                        const float* __restrict__ xsmall,
                        const float* __restrict__ temb, const float* __restrict__ kemb,
                        f16* __restrict__ xb, int N){
  int n = blockIdx.x; int j = threadIdx.x;
  if(n>=N) return;
  float v;
  if(j<32)       v = temb[xtype[n]*32 + j];
  else if(j<64)  v = kemb[xtok[n]*32 + (j-32)];
  else           v = xsmall[(size_t)n*64 + (j-64)];
  xb[(size_t)n*128 + j] = (f16)v;
}

// Wc[o2][K] = sum_k2 W_ih[o2,k2] * msg_W[K>>7][k2][K&127]
__global__ void k_wcomb(const float* __restrict__ W_ih, const float* __restrict__ msg_W,
                        float* __restrict__ Wc){
  int i = blockIdx.x*256 + threadIdx.x;
  if(i >= 147456) return;
  int o2 = i/384, K = i%384;
  const float* wr = W_ih + o2*128;
  const float* mc = msg_W + (K>>7)*16384 + (K&127);
  float acc = 0.f;
  #pragma unroll 4
  for(int k2=0;k2<128;k2++) acc += wr[k2]*mc[k2*128];
  Wc[i] = acc;
}

// mbp[t][o2] = sum_k2 W_ih[o2,k2]*msg_b[t,k2]
__global__ void k_mbp(const float* __restrict__ W_ih, const float* __restrict__ msg_b,
                      float* __restrict__ mbp){
  int i = blockIdx.x*256 + threadIdx.x;
  if(i >= 1152) return;
  int t = i/384, o2 = i%384;
  const float* wr = W_ih + o2*128;
  const float* mb = msg_b + t*128;
  float acc = 0.f;
  #pragma unroll 4
  for(int k2=0;k2<128;k2++) acc += wr[k2]*mb[k2];
  mbp[i] = acc;
}

// Pack weights f16, MFMA B-frag order: n = tile*32+(lane&31), k = ks*16+(lane>>5)*8+j
__global__ void k_wprep(const float* __restrict__ Wc, const float* __restrict__ W_hh,
                        f16* __restrict__ WpF){
  int i = blockIdx.x*256 + threadIdx.x;
  if(i >= GI_F + GH_F) return;
  float w; int lane, j;
  if(i < GI_F){
    int grp = i/512, rem = i%512;
    lane = rem/8; j = rem%8;
    int tile = grp/24, ks = grp%24;
    int n = tile*32 + (lane&31);
    int k = ks*16 + (lane>>5)*8 + j;
    w = Wc[n*384 + k];
  } else {
    int i2 = i - GI_F;
    int grp = i2/512, rem = i2%512;
    lane = rem/8; j = rem%8;
    int tile = grp/8, ks = grp%8;
    int n = tile*32 + (lane&31);
    int k = ks*16 + (lane>>5)*8 + j;
    w = W_hh[n*128 + k];
  }
  WpF[i] = (f16)w;
}

__global__ void k_hist3(const int* __restrict__ dst, const int* __restrict__ et,
                        int* __restrict__ deg3, int E){
  int e = blockIdx.x*blockDim.x + threadIdx.x;
  if(e<E) atomicAdd(&deg3[dst[e]*3 + et[e]], 1);
}

__global__ void k_scan1(const int* __restrict__ deg, int n, int* __restrict__ part, int* __restrict__ bsum){
  __shared__ int s[256];
  int t = threadIdx.x;
  int base = blockIdx.x*1024 + t*4;
  int v[4]; int sum=0;
  #pragma unroll
  for(int k=0;k<4;k++){ int i=base+k; int d=(i<n)?deg[i]:0; sum+=d; v[k]=sum; }
  s[t]=sum; __syncthreads();
  for(int off=1;off<256;off<<=1){
    int add = (t>=off)? s[t-off] : 0;
    __syncthreads();
    s[t]+=add;
    __syncthreads();
  }
  int excl = (t>0)? s[t-1] : 0;
  #pragma unroll
  for(int k=0;k<4;k++){ int i=base+k; if(i<n) part[i]=v[k]+excl; }
  if(t==255) bsum[blockIdx.x] = s[255];
}

__global__ void k_scan2(const int* __restrict__ bsum, int nb, int* __restrict__ carry){
  if(threadIdx.x==0 && blockIdx.x==0){
    int c=0;
    for(int b=0;b<nb;b++){ carry[b]=c; c+=bsum[b]; }
  }
}

__global__ void k_finalize(const int* __restrict__ part, const int* __restrict__ deg,
                           const int* __restrict__ carry, int n,
                           int* __restrict__ rowptr, int* __restrict__ cursor){
  int i = blockIdx.x*blockDim.x + threadIdx.x;
  if(i>=n) return;
  int incl = part[i] + carry[i>>10];
  rowptr[i+1] = incl;
  cursor[i] = incl - deg[i];
  if(i==0) rowptr[0]=0;
}

// pay stores BYTE offsets of source rows (src*256); max 25.6MB < 2^31.
__global__ void k_fill3(const int* __restrict__ src, const int* __restrict__ dst,
                        const int* __restrict__ et, int* __restrict__ cursor,
                        int* __restrict__ pay, int E){
  int e = blockIdx.x*blockDim.x + threadIdx.x;
  if(e>=E) return;
  int pos = atomicAdd(&cursor[dst[e]*3 + et[e]], 1);
  pay[pos] = src[e] << 8;     // byte offset: 128 f16 * 2B = 256B/row
}

// gather: 4 nodes per wave (one per 16-lane quarter), lane covers 8 f16
// cols via one v8hf 16B load. f16 packed accumulation (v_pk_add_f16),
// byte-offset pay -> no mul in address path. At its memory floor.
__global__ void k_gather3_f(const f16* __restrict__ xb, const int* __restrict__ rp3,
                            const int* __restrict__ pay, f16* __restrict__ s, int N){
  int tid = threadIdx.x;
  int lane = tid & 63;
  int h = lane >> 4;          // quarter = node select within wave
  int c8b = (lane & 15)*16;   // col byte offset within row
  const char* xbb = (const char*)xb;
  int n = blockIdx.x*16 + (tid>>6)*4 + h;
  bool valid = (n < N);
  int nn = valid ? n : (N-1);
  int b = nn*3;
  int lo = rp3[b], e0 = rp3[b+1], e1 = rp3[b+2], hi = rp3[b+3];
  if(!valid){ lo = 0; e0 = 0; e1 = 0; hi = 0; }
  v8hf a0 = {}, a1 = {}, a2 = {};
  int len = hi - lo;
  int t1 = lo + len/3;
  int t2 = lo + (2*len)/3;
  int iA = lo, iB = t1, iC = t2;
  while(iA < t1 && iB < t2 && iC < hi){
    int pA = pay[iA], pB = pay[iB], pC = pay[iC];
    v8hf uA = *(const v8hf*)(xbb + pA + c8b);
    v8hf uB = *(const v8hf*)(xbb + pB + c8b);
    v8hf uC = *(const v8hf*)(xbb + pC + c8b);
    if(iA < e0)      a0 += uA;
    else if(iA < e1) a1 += uA;
    else             a2 += uA;
    if(iB < e0)      a0 += uB;
    else if(iB < e1) a1 += uB;
    else             a2 += uB;
    if(iC < e0)      a0 += uC;
    else if(iC < e1) a1 += uC;
    else             a2 += uC;
    iA++; iB++; iC++;
  }
  for(; iA < t1; iA++){
    v8hf u = *(const v8hf*)(xbb + pay[iA] + c8b);
    if(iA < e0)      a0 += u;
    else if(iA < e1) a1 += u;
    else             a2 += u;
  }
  for(; iB < t2; iB++){
    v8hf u = *(const v8hf*)(xbb + pay[iB] + c8b);
    if(iB < e0)      a0 += u;
    else if(iB < e1) a1 += u;
    else             a2 += u;
  }
  for(; iC < hi; iC++){
    v8hf u = *(const v8hf*)(xbb + pay[iC] + c8b);
    if(iC < e0)      a0 += u;
    else if(iC < e1) a1 += u;
    else             a2 += u;
  }
  if(valid){
    char* sb = (char*)s + (size_t)n*768 + c8b;
    *(v8hf*)(sb)       = a0;
    *(v8hf*)(sb + 256) = a1;
    *(v8hf*)(sb + 512) = a2;
  }
}

// Fused gi+gh GEMM + GRU, f16 master. 32 rows/block, 256 threads (4 waves).
// Wave w col-tiles {w,w+4,w+8} = gates r,z,n for feature slice jf.
// acc0,acc1 accumulate gi AND gh (summed gates); acc2 packed to gp2 after
// gi; accn fresh for gh-n. Peak acc 48 AGPR -> ~150 unified -> 3 w/SIMD.
#define SSTR 392   // 384+8
#define XSTR 136   // 128+8
__global__ __launch_bounds__(256,3) void k_mega3g(
    const f16* __restrict__ xb_old, f16* __restrict__ xb_new,
    const f16* __restrict__ s, const f16* __restrict__ WpF,
    const int* __restrict__ deg3, const float* __restrict__ mbp,
    const float* __restrict__ b_ih, const float* __restrict__ b_hh, int M)
{
  __shared__ f16 Ss[32*SSTR];   // 24.5 KB
  __shared__ f16 Ax[32*XSTR];   //  8.5 KB
  __shared__ float Dg[96];      // deg3 for this block's 32 rows
  int tid = threadIdx.x, lane = tid & 63, w = tid >> 6;
  int lrow = lane & 31, q = lane >> 5;
  int row0 = blockIdx.x * 32;

  // stage xb rows -> Ax: 512 chunks, 2/thread
  #pragma unroll
  for(int p=0;p<2;p++){
    int ch = tid + p*256;
    int row = ch>>4, c8 = (ch&15)*8;
    int gr = row0 + row; if(gr >= M) gr = M-1;
    *(v8hf*)&Ax[row*XSTR + c8] = *(const v8hf*)(xb_old + (size_t)gr*128 + c8);
  }
  // stage s rows -> Ss: 1536 chunks, 6/thread
  #pragma unroll
  for(int p=0;p<6;p++){
    int ch = tid + p*256;
    int row = ch/48, c8 = (ch%48)*8;
    int gr = row0 + row; if(gr >= M) gr = M-1;
    *(v8hf*)&Ss[row*SSTR + c8] = *(const v8hf*)(s + (size_t)gr*384 + c8);
  }
  // stage deg3 -> Dg
  if(tid < 96){
    int node = row0 + tid/3;
    Dg[tid] = (node < M) ? (float)deg3[node*3 + (tid - (tid/3)*3)] : 0.f;
  }
  __syncthreads();

  // ---- gi phase: K=384 over Ss; acc0/acc1/acc2 = gates r/z/n ----
  v16f acc0 = {}, acc1 = {}, acc2 = {};
  #pragma unroll
  for(int ks=0; ks<24; ks++){
    int kb = ks*16 + q*8;
    v8hf a0 = *(const v8hf*)&Ss[lrow*SSTR + kb];
    v8hf b0 = *(const v8hf*)(WpF + (size_t)((0*4+w)*24 + ks)*512 + lane*8);
    v8hf b1 = *(const v8hf*)(WpF + (size_t)((1*4+w)*24 + ks)*512 + lane*8);
    v8hf b2 = *(const v8hf*)(WpF + (size_t)((2*4+w)*24 + ks)*512 + lane*8);
    acc0 = __builtin_amdgcn_mfma_f32_32x32x16_f16(a0, b0, acc0, 0,0,0);
    acc1 = __builtin_amdgcn_mfma_f32_32x32x16_f16(a0, b1, acc1, 0,0,0);
    acc2 = __builtin_amdgcn_mfma_f32_32x32x16_f16(a0, b2, acc2, 0,0,0);
  }
  // pack ONLY gi-n to f16 pairs (8 regs); acc2's AGPRs become free for accn
  v2hf gp2[8];
  #pragma unroll
  for(int rp=0; rp<8; rp++){
    v2hf t; t[0] = (f16)acc2[2*rp]; t[1] = (f16)acc2[2*rp+1];
    gp2[rp] = t;
  }

  // ---- gh phase: K=128 over Ax; r,z continue into acc0/acc1; n fresh ----
  v16f accn = {};
  #pragma unroll
  for(int ks=0; ks<8; ks++){
    int kb = ks*16 + q*8;
    v8hf a0 = *(const v8hf*)&Ax[lrow*XSTR + kb];
    v8hf b0 = *(const v8hf*)(WpF + GI_F + (size_t)((0*4+w)*8 + ks)*512 + lane*8);
    v8hf b1 = *(const v8hf*)(WpF + GI_F + (size_t)((1*4+w)*8 + ks)*512 + lane*8);
    v8hf b2 = *(const v8hf*)(WpF + GI_F + (size_t)((2*4+w)*8 + ks)*512 + lane*8);
    acc0 = __builtin_amdgcn_mfma_f32_32x32x16_f16(a0, b0, acc0, 0,0,0);
    acc1 = __builtin_amdgcn_mfma_f32_32x32x16_f16(a0, b1, acc1, 0,0,0);
    accn = __builtin_amdgcn_mfma_f32_32x32x16_f16(a0, b2, accn, 0,0,0);
  }

  __syncthreads();   // all waves' gh reads of Ax complete before in-place write

  // GRU epilogue. jf = this lane's feature; x_old from LDS.
  int jf = w*32 + lrow;
  float br = b_ih[jf]     + b_hh[jf];        // r-gate combined bias
  float bz = b_ih[128+jf] + b_hh[128+jf];    // z-gate combined bias
  float bi2 = b_ih[256+jf], bh2 = b_hh[256+jf];
  float mb[3][3];
  #pragma unroll
  for(int t=0;t<3;t++){
    mb[t][0] = mbp[t*384 + jf];
    mb[t][1] = mbp[t*384 + 128 + jf];
    mb[t][2] = mbp[t*384 + 256 + jf];
  }
  int rq4 = 4*q;
  #pragma unroll
  for(int r=0;r<16;r++){
    int gl = (r&3) + 8*(r>>2) + rq4;          // local row 0..31
    float d0 = Dg[gl*3], d1 = Dg[gl*3+1], d2 = Dg[gl*3+2];
    float rg = sigf(acc0[r] + br + d0*mb[0][0] + d1*mb[1][0] + d2*mb[2][0]);
    float zg = sigf(acc1[r] + bz + d0*mb[0][1] + d1*mb[1][1] + d2*mb[2][1]);
    float in_ = (float)gp2[r>>1][r&1] + bi2 + d0*mb[0][2] + d1*mb[1][2] + d2*mb[2][2];
    float hn  = accn[r] + bh2;
    float nn = tanhf_fast(in_ + rg*hn);
    float xo = (float)Ax[gl*XSTR + jf];
    Ax[gl*XSTR + jf] = (f16)((1.f - zg)*nn + zg*xo);   // in-place, own slot
  }
  __syncthreads();
  // coalesced writeback from Ax
  #pragma unroll
  for(int p=0;p<2;p++){
    int ch = tid + p*256;
    int row = ch>>4, c8 = (ch&15)*8;
    int gr = row0 + row;
    if(gr < M)
      *(v8hf*)(xb_new + (size_t)gr*128 + c8) = *(const v8hf*)&Ax[row*XSTR + c8];
  }
}

__device__ __forceinline__ int lb_batch(const int* __restrict__ batch, int N, int g){
  int lo=0, hi=N;
  while(lo<hi){ int mid=(lo+hi)>>1; if(batch[mid]<g) lo=mid+1; else hi=mid; }
  return lo;
}

__global__ void k_pool2(const f16* __restrict__ xb, const int* __restrict__ batch,
                        float* __restrict__ pooled, int N){
  int g = blockIdx.x, slice = blockIdx.y;
  int j = threadIdx.x;
  int lo = lb_batch(batch,N,g), hi = lb_batch(batch,N,g+1);
  float acc = 0.f;
  for(int r=lo+slice; r<hi; r+=32) acc += (float)xb[(size_t)r*128 + j];
  atomicAdd(&pooled[g*128+j], acc);
}

__global__ void k_head(const float* __restrict__ pooled, const int* __restrict__ batch, int N,
                       const float* __restrict__ W1, const float* __restrict__ b1,
                       const float* __restrict__ W2, const float* __restrict__ b2,
                       float* __restrict__ out){
  int g = blockIdx.x; int j = threadIdx.x;
  __shared__ float p[128];
  __shared__ float red[128];
  int lo = lb_batch(batch,N,g), hi = lb_batch(batch,N,g+1);
  float c = (float)(hi-lo); if(c < 1.f) c = 1.f;
  p[j] = pooled[g*128+j] / c;
  __syncthreads();
  float acc = b1[j];
  #pragma unroll 4
  for(int i=0;i<128;i++) acc += W1[j*128+i]*p[i];
  float v = (acc>0.f?acc:0.f) * W2[j];
  red[j] = v; __syncthreads();
  for(int s=64;s>0;s>>=1){ if(j<s) red[j]+=red[j+s]; __syncthreads(); }
  if(j==0) out[g] = red[0] + b2[0];
}

extern "C" void kernel_launch(void* const* d_in, const int* in_sizes, int n_in,
                              void* d_out, int out_size, void* d_ws, size_t ws_size,
                              hipStream_t stream){
  const int*   x_type    = (const int*)d_in[0];
  const int*   x_tok     = (const int*)d_in[1];
  const float* x_small   = (const float*)d_in[2];
  const int*   edge_index= (const int*)d_in[3];
  const int*   edge_type = (const int*)d_in[4];
  const int*   batch     = (const int*)d_in[5];
  const float* type_emb  = (const float*)d_in[6];
  const float* tok_emb   = (const float*)d_in[7];
  const float* msg_W     = (const float*)d_in[8];
  const float* msg_b     = (const float*)d_in[9];
  const float* W_ih      = (const float*)d_in[10];
  const float* W_hh      = (const float*)d_in[11];
  const float* b_ih      = (const float*)d_in[12];
  const float* b_hh      = (const float*)d_in[13];
  const float* pW1       = (const float*)d_in[14];
  const float* pb1       = (const float*)d_in[15];
  const float* pW2       = (const float*)d_in[16];
  const float* pb2       = (const float*)d_in[17];
  float* out = (float*)d_out;

  int N = in_sizes[0];
  int E = in_sizes[3]/2;
  const int* src = edge_index;
  const int* dst = edge_index + E;
  int n3 = 3*N;
  int nch = (n3+1023)/1024;

  char* w = (char*)d_ws;
  size_t off = 0;
  auto alloc = [&](size_t bytes)->char*{ char* p = w + off; off += (bytes + 511) & ~511ull; return p; };
  f16*   xb0    = (f16*)alloc((size_t)N*128*2);       // ping (25.6 MB)
  f16*   xb1    = (f16*)alloc((size_t)N*128*2);       // pong (25.6 MB)
  f16*   s      = (f16*)alloc((size_t)N*384*2);       // gathered sums (76.8 MB)
  int*   deg3   = (int*)alloc((size_t)n3*4);
  int*   part   = (int*)alloc((size_t)n3*4);
  int*   rp3    = (int*)alloc((size_t)(n3+1)*4);
  int*   cursor = (int*)alloc((size_t)n3*4);
  int*   pay    = (int*)alloc((size_t)E*4);
  int*   bsum   = (int*)alloc((size_t)nch*4);
  int*   carry  = (int*)alloc((size_t)nch*4);
  float* Wc     = (float*)alloc((size_t)147456*4);
  f16*   WpF    = (f16*)alloc((size_t)(GI_F+GH_F)*2);
  float* mbp    = (float*)alloc((size_t)1152*4);
  float* pooled = (float*)alloc(64*128*4);
  if(off > ws_size){
    k_diag<<<1,64,0,stream>>>(out, out_size, 1.0e6f + (float)(ws_size>>20));
    return;
  }

  const int tb = 256;
  hipMemsetAsync(deg3, 0, (size_t)n3*4, stream);
  k_wcomb   <<<576, 256, 0, stream>>>(W_ih, msg_W, Wc);
  k_mbp     <<<5, 256, 0, stream>>>(W_ih, msg_b, mbp);
  k_wprep   <<<(GI_F+GH_F+255)/256, 256, 0, stream>>>(Wc, W_hh, WpF);
  k_hist3   <<<(E+tb-1)/tb, tb, 0, stream>>>(dst, edge_type, deg3, E);
  k_scan1   <<<nch, 256, 0, stream>>>(deg3, n3, part, bsum);
  k_scan2   <<<1, 64, 0, stream>>>(bsum, nch, carry);
  k_finalize<<<(n3+tb-1)/tb, tb, 0, stream>>>(part, deg3, carry, n3, rp3, cursor);
  k_fill3   <<<(E+tb-1)/tb, tb, 0, stream>>>(src, dst, edge_type, cursor, pay, E);
  k_embed   <<<N, 128, 0, stream>>>(x_type, x_tok, x_small, type_emb, tok_emb, xb0, N);

  int nblk = (N+31)/32;
  f16* xin = xb0;
  f16* xout = xb1;
  for(int it=0; it<8; it++){
    k_gather3_f<<<(N+15)/16, 256, 0, stream>>>(xin, rp3, pay, s, N);
    k_mega3g   <<<nblk, 256, 0, stream>>>(xin, xout, s, WpF, deg3, mbp, b_ih, b_hh, N);
    f16* tmp = xin; xin = xout; xout = tmp;
  }
  // final state is in xin after the swap
  hipMemsetAsync(pooled, 0, 64*128*4, stream);
  k_pool2<<<dim3(64,32), 128, 0, stream>>>(xin, batch, pooled, N);
  k_head <<<64, 128, 0, stream>>>(pooled, batch, N, pW1, pb1, pW2, pb2, out);
}